// Round 6
// baseline (417.170 us; speedup 1.0000x reference)
//
#include <hip/hip_runtime.h>

// All tensors float32. Math structure exploited:
//  - softmax over axis of size 1 == 1.0 -> attn all-ones, Wa/ba dead.
//  - weighted = row-sum of tanh(agg), broadcast over COLUMNS (N==D quirk).
//  - lig_p = nf@Wl.T + const  ->  x0[h,i,j] = PL[i,h] + PR[j,h] + c[h]
//  - conv1/2/3 fully fused, x0 generated on the fly (no 128MB tensor).
//  - gnn GEMM and convs on f16 MFMA, f32 accumulate.
//  - conv LDS ALIASED (weights live in dead phases of xs/ys buffers):
//    46,336 B total -> 3 blocks/CU (round-5 lesson: 65,152 B rounded to the
//    64-KiB boundary and collapsed occupancy to 1 block/CU).

typedef _Float16 half8 __attribute__((ext_vector_type(8)));
typedef _Float16 half4 __attribute__((ext_vector_type(4)));
typedef float    f32x4 __attribute__((ext_vector_type(4)));

__device__ __forceinline__ short f2h_bits(float f){
    _Float16 h = (_Float16)f;          // RNE
    return __builtin_bit_cast(short, h);
}
__device__ __forceinline__ half8 pack2(const float4& x, const float4& y){
    half8 r;
    r[0] = (_Float16)x.x; r[1] = (_Float16)x.y;
    r[2] = (_Float16)x.z; r[3] = (_Float16)x.w;
    r[4] = (_Float16)y.x; r[5] = (_Float16)y.y;
    r[6] = (_Float16)y.z; r[7] = (_Float16)y.w;
    return r;
}
__device__ __forceinline__ half4 pack4(const float4& x){
    half4 r;
    r[0] = (_Float16)x.x; r[1] = (_Float16)x.y;
    r[2] = (_Float16)x.z; r[3] = (_Float16)x.w;
    return r;
}

// ci-block swizzle for conv LDS tiles (round-4 verified layout)
#define SWZ(c) ((((c) >> 1) & 3) << 3)

// ---------------------------------------------------------------------------
// K1 (MFMA): agg = tanh([nf|ef]@[Wn|We].T + bn + be); per-block row-sums over
// its 64 d-columns -> part[cx][dblk][row]. BM=BN=64, BK=64, 256 thr (4 waves,
// wave-tile 32x32), grid (16,16,2). LDS tiles f16, granule XOR swizzle.
// ---------------------------------------------------------------------------
__global__ __launch_bounds__(256) void gnn_kernel(
    const float* __restrict__ lig_nf, const float* __restrict__ lig_ef,
    const float* __restrict__ rec_nf, const float* __restrict__ rec_ef,
    const float* __restrict__ Wn, const float* __restrict__ We,
    const float* __restrict__ bn, const float* __restrict__ be,
    float* __restrict__ part)   // [2][16][1024]
{
    __shared__ __attribute__((aligned(16))) short As[64 * 64];
    __shared__ __attribute__((aligned(16))) short Bs[64 * 64];
    __shared__ float red[64][2];

    const int t  = threadIdx.x;
    const int cx = blockIdx.z;
    const float* A0 = cx ? rec_nf : lig_nf;
    const float* A1 = cx ? rec_ef : lig_ef;
    const int j0 = blockIdx.x * 64;
    const int d0 = blockIdx.y * 64;

    const int wid  = t >> 6;
    const int wm   = wid >> 1, wn = wid & 1;
    const int lane = t & 63;
    const int lr   = lane & 15;   // A: row, B: col, C: col
    const int lg   = lane >> 4;   // k-granule / C row group

    f32x4 acc[2][2];
    #pragma unroll
    for (int m = 0; m < 2; ++m)
        #pragma unroll
        for (int n = 0; n < 2; ++n)
            acc[m][n] = (f32x4){0.f, 0.f, 0.f, 0.f};

    const int srow   = t >> 2;    // staging row 0..63
    const int schunk = t & 3;     // 16-float chunk of the 64-wide K slab
    const int sswz   = srow & 7;

    for (int kb = 0; kb < 2048; kb += 64){
        const float* Asrc = (kb < 1024) ? A0 : A1;
        const float* Bsrc = (kb < 1024) ? Wn : We;
        const int kcol = (kb & 1023) + schunk * 16;
        float4 av[4], bv[4];
        const float* ap = Asrc + (size_t)(j0 + srow) * 1024 + kcol;
        const float* bp = Bsrc + (size_t)(d0 + srow) * 1024 + kcol;
        #pragma unroll
        for (int q = 0; q < 4; ++q){
            av[q] = *reinterpret_cast<const float4*>(ap + q * 4);
            bv[q] = *reinterpret_cast<const float4*>(bp + q * 4);
        }
        __syncthreads();   // previous iter's LDS reads done
        const int g0 = ((schunk * 2)     ^ sswz) * 8;
        const int g1 = ((schunk * 2 + 1) ^ sswz) * 8;
        *reinterpret_cast<half8*>(&As[srow * 64 + g0]) = pack2(av[0], av[1]);
        *reinterpret_cast<half8*>(&As[srow * 64 + g1]) = pack2(av[2], av[3]);
        *reinterpret_cast<half8*>(&Bs[srow * 64 + g0]) = pack2(bv[0], bv[1]);
        *reinterpret_cast<half8*>(&Bs[srow * 64 + g1]) = pack2(bv[2], bv[3]);
        __syncthreads();

        #pragma unroll
        for (int ks = 0; ks < 2; ++ks){
            half8 Af[2], Bf[2];
            #pragma unroll
            for (int m = 0; m < 2; ++m){
                int row = wm * 32 + m * 16 + lr;
                int g   = ((ks * 4 + lg) ^ (row & 7)) * 8;
                Af[m] = *reinterpret_cast<const half8*>(&As[row * 64 + g]);
            }
            #pragma unroll
            for (int n = 0; n < 2; ++n){
                int col = wn * 32 + n * 16 + lr;
                int g   = ((ks * 4 + lg) ^ (col & 7)) * 8;
                Bf[n] = *reinterpret_cast<const half8*>(&Bs[col * 64 + g]);
            }
            #pragma unroll
            for (int m = 0; m < 2; ++m)
                #pragma unroll
                for (int n = 0; n < 2; ++n)
                    acc[m][n] = __builtin_amdgcn_mfma_f32_16x16x32_f16(
                        Af[m], Bf[n], acc[m][n], 0, 0, 0);
        }
    }

    // epilogue: bias + tanh + reduce over the block's 64 d-columns
    float rowsum[2][4];
    #pragma unroll
    for (int m = 0; m < 2; ++m)
        #pragma unroll
        for (int jj = 0; jj < 4; ++jj) rowsum[m][jj] = 0.f;
    #pragma unroll
    for (int n = 0; n < 2; ++n){
        int d = d0 + wn * 32 + n * 16 + lr;
        float bias = bn[d] + be[d];
        #pragma unroll
        for (int m = 0; m < 2; ++m)
            #pragma unroll
            for (int jj = 0; jj < 4; ++jj)
                rowsum[m][jj] += tanhf(acc[m][n][jj] + bias);
    }
    #pragma unroll
    for (int mask = 1; mask < 16; mask <<= 1)
        #pragma unroll
        for (int m = 0; m < 2; ++m)
            #pragma unroll
            for (int jj = 0; jj < 4; ++jj)
                rowsum[m][jj] += __shfl_xor(rowsum[m][jj], mask);
    __syncthreads();
    if (lr == 0){
        #pragma unroll
        for (int m = 0; m < 2; ++m)
            #pragma unroll
            for (int jj = 0; jj < 4; ++jj)
                red[wm * 32 + m * 16 + lg * 4 + jj][wn] = rowsum[m][jj];
    }
    __syncthreads();
    if (t < 64)
        part[(size_t)cx * 16384 + (size_t)blockIdx.y * 1024 + j0 + t]
            = red[t][0] + red[t][1];
}

// ---------------------------------------------------------------------------
// K2a: PL[i,h] = sum_j nf[i,j]*Wl[h,j]; PR analog. grid (128,2), block 256
// ---------------------------------------------------------------------------
__global__ __launch_bounds__(256) void proj_kernel(
    const float* __restrict__ lig_nf, const float* __restrict__ rec_nf,
    const float* __restrict__ W_hopi, float* __restrict__ PL, float* __restrict__ PR)
{
    const int t  = threadIdx.x;
    const int cx = blockIdx.y;
    const float* nf = cx ? rec_nf : lig_nf;
    const float* W  = W_hopi + (cx ? 1024 : 0);
    float* outp     = cx ? PR : PL;
    const int h = t & 31;
    const int i = blockIdx.x * 8 + (t >> 5);
    const float* nrow = nf + (size_t)i * 1024;
    const float* wrow = W + (size_t)h * 2048;
    float s0 = 0.f, s1 = 0.f;
    #pragma unroll 4
    for (int j = 0; j < 1024; j += 8){
        float4 a0 = *reinterpret_cast<const float4*>(nrow + j);
        float4 b0 = *reinterpret_cast<const float4*>(wrow + j);
        float4 a1 = *reinterpret_cast<const float4*>(nrow + j + 4);
        float4 b1 = *reinterpret_cast<const float4*>(wrow + j + 4);
        s0 = fmaf(a0.x, b0.x, s0); s0 = fmaf(a0.y, b0.y, s0);
        s0 = fmaf(a0.z, b0.z, s0); s0 = fmaf(a0.w, b0.w, s0);
        s1 = fmaf(a1.x, b1.x, s1); s1 = fmaf(a1.y, b1.y, s1);
        s1 = fmaf(a1.z, b1.z, s1); s1 = fmaf(a1.w, b1.w, s1);
    }
    outp[(size_t)i * 32 + h] = s0 + s1;
}

// ---------------------------------------------------------------------------
// K2b: w[j] = block-sum of part; c[h] = b_hopi[h] + wL.Wl[h] + wR.Wr[h]
// ---------------------------------------------------------------------------
__global__ __launch_bounds__(256) void cvec_kernel(
    const float* __restrict__ W_hopi, const float* __restrict__ b_hopi,
    const float* __restrict__ part, float* __restrict__ cvec)
{
    __shared__ float ws_l[1024];
    __shared__ float ws_r[1024];
    __shared__ float red[256];
    const int t = threadIdx.x;
    for (int j = t; j < 1024; j += 256){
        float sl = 0.f, sr = 0.f;
        #pragma unroll
        for (int b = 0; b < 16; ++b){
            sl += part[b * 1024 + j];
            sr += part[16384 + b * 1024 + j];
        }
        ws_l[j] = sl; ws_r[j] = sr;
    }
    __syncthreads();
    const int h = t & 31;
    const int seg = t >> 5;
    float s = 0.f;
    for (int j = seg * 128; j < seg * 128 + 128; ++j){
        s = fmaf(ws_l[j], W_hopi[(size_t)h * 2048 + j], s);
        s = fmaf(ws_r[j], W_hopi[(size_t)h * 2048 + 1024 + j], s);
    }
    red[t] = s;
    __syncthreads();
    if (t < 32){
        float tot = b_hopi[t];
        #pragma unroll
        for (int g = 0; g < 8; ++g) tot += red[g * 32 + t];
        cvec[t] = tot;
    }
}

// ---------------------------------------------------------------------------
// K3: fused conv1+relu -> conv2+relu -> conv3 on f16 MFMA (round-4 layout).
// LDS aliasing: wB1 lives in ysbuf (dead until Bf1 hoisted to regs);
// wB2 restaged into xsbuf (dead after conv1). Total 46,336 B -> 3 blocks/CU.
// block 512 (8 waves), grid 64x64.
// ---------------------------------------------------------------------------
__global__ __launch_bounds__(512, 6) void conv_kernel(
    const float* __restrict__ PL, const float* __restrict__ PR,
    const float* __restrict__ cvec,
    const float* __restrict__ w1, const float* __restrict__ b1,
    const float* __restrict__ w2, const float* __restrict__ b2,
    const float* __restrict__ w3, const float* __restrict__ b3,
    float* __restrict__ outp)
{
    __shared__ __attribute__((aligned(16))) short xsbuf[20 * 20 * 32]; // 25600 B; later wB2
    __shared__ __attribute__((aligned(16))) short ysbuf[18 * 18 * 32]; // 20736 B; first wB1

    short* xs  = xsbuf;
    short* ys  = ysbuf;
    short* wB1 = ysbuf;    // 9216 shorts <= 10368
    short* wB2 = xsbuf;    // 9216 shorts <= 12800

    const int t    = threadIdx.x;
    const int oy0  = blockIdx.y * 16;
    const int ox0  = blockIdx.x * 16;
    const int wid  = t >> 6;
    const int lane = t & 63;
    const int lr   = lane & 15;
    const int lg   = lane >> 4;

    // ---- stage x0 tile: 400 pixels x 32 ci, float4 path, div-free walk ----
    {
        const int cp  = (t & 7) * 4;      // ci quad (4-aligned; SWZ keeps alignment)
        const int grp = t >> 3;           // 64 pixels per pass
        int ry = grp / 20;
        int rx = grp - ry * 20;
        #pragma unroll
        for (int pass = 0; pass < 7; ++pass){
            int pp = grp + pass * 64;
            if (pp < 400){
                int a = oy0 - 2 + ry, b = ox0 - 2 + rx;
                float4 v = make_float4(0.f, 0.f, 0.f, 0.f);
                if (a >= 0 && a < 1024 && b >= 0 && b < 1024){
                    float4 pl = *reinterpret_cast<const float4*>(PL + a * 32 + cp);
                    float4 pr = *reinterpret_cast<const float4*>(PR + b * 32 + cp);
                    float4 cv = *reinterpret_cast<const float4*>(cvec + cp);
                    v = make_float4(pl.x + pr.x + cv.x, pl.y + pr.y + cv.y,
                                    pl.z + pr.z + cv.z, pl.w + pr.w + cv.w);
                }
                *reinterpret_cast<half4*>(&xs[pp * 32 + (cp ^ SWZ(rx))]) = pack4(v);
            }
            ry += 3; rx += 4;
            if (rx >= 20){ rx -= 20; ry += 1; }
        }
    }
    // ---- stage conv1 weights into wB1 (coalesced 64B reads per 16 lanes) ----
    {
        const int co_s = t >> 4;          // 0..31
        const int ls   = t & 15;
        #pragma unroll
        for (int kk = 0; kk < 18; ++kk){
            int k   = ls + (kk << 4);     // 0..287
            int ci  = k / 9;
            int tap = k - ci * 9;
            wB1[(tap * 32 + co_s) * 32 + (ci ^ SWZ(co_s))] =
                f2h_bits(w1[co_s * 288 + k]);
        }
    }
    __syncthreads();

    // ================= conv1: 324 outputs (18x18) =========
    {
        half8 Bf[2][9];
        float bias[2];
        #pragma unroll
        for (int n = 0; n < 2; ++n){
            int co = n * 16 + lr;
            bias[n] = b1[co];
            #pragma unroll
            for (int tap = 0; tap < 9; ++tap)
                Bf[n][tap] = *reinterpret_cast<const half8*>(
                    &wB1[(tap * 32 + co) * 32 + ((lg * 8) ^ SWZ(co))]);
        }
        __syncthreads();   // all waves finished reading wB1 before ys writes

        for (int s = wid; s < 21; s += 8){
            int praw = s * 16 + lr;
            int p  = praw > 323 ? 323 : praw;
            int ry = p / 18;
            int rx = p - ry * 18;
            f32x4 acc0 = {0.f, 0.f, 0.f, 0.f};
            f32x4 acc1 = {0.f, 0.f, 0.f, 0.f};
            #pragma unroll
            for (int tap = 0; tap < 9; ++tap){
                const int dy = tap / 3, dx = tap - (tap / 3) * 3;
                int pix = (ry + dy) * 20 + rx + dx;
                half8 A = *reinterpret_cast<const half8*>(
                    &xs[pix * 32 + ((lg * 8) ^ SWZ(rx + dx))]);
                acc0 = __builtin_amdgcn_mfma_f32_16x16x32_f16(A, Bf[0][tap], acc0, 0, 0, 0);
                acc1 = __builtin_amdgcn_mfma_f32_16x16x32_f16(A, Bf[1][tap], acc1, 0, 0, 0);
            }
            // epilogue: single div + wrap-increment
            int po  = s * 16 + lg * 4;
            int ryo = po / 18;
            int rxo = po - ryo * 18;
            #pragma unroll
            for (int j = 0; j < 4; ++j){
                if (po + j < 324){
                    int gy = oy0 - 1 + ryo, gx = ox0 - 1 + rxo;
                    bool ok = (gy >= 0) & (gy < 1024) & (gx >= 0) & (gx < 1024);
                    float v0 = ok ? fmaxf(acc0[j] + bias[0], 0.f) : 0.f;
                    float v1 = ok ? fmaxf(acc1[j] + bias[1], 0.f) : 0.f;
                    int sw = SWZ(rxo);
                    ys[(po + j) * 32 + (lr ^ sw)]        = f2h_bits(v0);
                    ys[(po + j) * 32 + ((16 + lr) ^ sw)] = f2h_bits(v1);
                }
                rxo += 1;
                if (rxo == 18){ rxo = 0; ryo += 1; }
            }
        }
    }
    __syncthreads();
    // ---- stage conv2 weights into wB2 (= xsbuf, xs is dead) ----
    {
        const int co_s = t >> 4;
        const int ls   = t & 15;
        #pragma unroll
        for (int kk = 0; kk < 18; ++kk){
            int k   = ls + (kk << 4);
            int ci  = k / 9;
            int tap = k - ci * 9;
            wB2[(tap * 32 + co_s) * 32 + (ci ^ SWZ(co_s))] =
                f2h_bits(w2[co_s * 288 + k]);
        }
    }
    __syncthreads();

    // ================= conv2 + conv3: 256 outputs =========
    {
        half8 Bf[2][9];
        float bias[2], w3v[2];
        #pragma unroll
        for (int n = 0; n < 2; ++n){
            int co = n * 16 + lr;
            bias[n] = b2[co];
            w3v[n]  = w3[co];
            #pragma unroll
            for (int tap = 0; tap < 9; ++tap)
                Bf[n][tap] = *reinterpret_cast<const half8*>(
                    &wB2[(tap * 32 + co) * 32 + ((lg * 8) ^ SWZ(co))]);
        }
        const float b3v = b3[0];
        for (int s = wid; s < 16; s += 8){
            int p  = s * 16 + lr;
            int ry = p >> 4;
            int rx = p & 15;
            f32x4 acc0 = {0.f, 0.f, 0.f, 0.f};
            f32x4 acc1 = {0.f, 0.f, 0.f, 0.f};
            #pragma unroll
            for (int tap = 0; tap < 9; ++tap){
                const int dy = tap / 3, dx = tap - (tap / 3) * 3;
                int pix = (ry + dy) * 18 + rx + dx;
                half8 A = *reinterpret_cast<const half8*>(
                    &ys[pix * 32 + ((lg * 8) ^ SWZ(rx + dx))]);
                acc0 = __builtin_amdgcn_mfma_f32_16x16x32_f16(A, Bf[0][tap], acc0, 0, 0, 0);
                acc1 = __builtin_amdgcn_mfma_f32_16x16x32_f16(A, Bf[1][tap], acc1, 0, 0, 0);
            }
            float part[4];
            #pragma unroll
            for (int j = 0; j < 4; ++j)
                part[j] = w3v[0] * fmaxf(acc0[j] + bias[0], 0.f)
                        + w3v[1] * fmaxf(acc1[j] + bias[1], 0.f);
            #pragma unroll
            for (int m = 1; m < 16; m <<= 1)
                #pragma unroll
                for (int j = 0; j < 4; ++j)
                    part[j] += __shfl_xor(part[j], m);
            if (lr == 0){
                float4 o = make_float4(part[0] + b3v, part[1] + b3v,
                                       part[2] + b3v, part[3] + b3v);
                *reinterpret_cast<float4*>(outp + (size_t)(oy0 + s) * 1024 + ox0 + lg * 4) = o;
            }
        }
    }
}

// ---------------------------------------------------------------------------
extern "C" void kernel_launch(void* const* d_in, const int* in_sizes, int n_in,
                              void* d_out, int out_size, void* d_ws, size_t ws_size,
                              hipStream_t stream)
{
    const float* lig_nf = (const float*)d_in[0];
    const float* lig_ef = (const float*)d_in[1];
    const float* rec_nf = (const float*)d_in[3];
    const float* rec_ef = (const float*)d_in[4];
    const float* Wn     = (const float*)d_in[6];
    const float* bn     = (const float*)d_in[7];
    const float* We     = (const float*)d_in[8];
    const float* be     = (const float*)d_in[9];
    const float* W_hopi = (const float*)d_in[12];
    const float* b_hopi = (const float*)d_in[13];
    const float* w1     = (const float*)d_in[14];
    const float* b1     = (const float*)d_in[15];
    const float* w2     = (const float*)d_in[16];
    const float* b2     = (const float*)d_in[17];
    const float* w3     = (const float*)d_in[18];
    const float* b3     = (const float*)d_in[19];
    float* outp = (float*)d_out;

    float* part = (float*)d_ws;                               // [2][16][1024]
    float* PL   = (float*)((char*)d_ws + 131072);
    float* PR   = (float*)((char*)d_ws + 262144);
    float* cvec = (float*)((char*)d_ws + 393216);

    dim3 g1(16, 16, 2);
    gnn_kernel<<<g1, 256, 0, stream>>>(lig_nf, lig_ef, rec_nf, rec_ef,
                                       Wn, We, bn, be, part);
    dim3 g2(128, 2);
    proj_kernel<<<g2, 256, 0, stream>>>(lig_nf, rec_nf, W_hopi, PL, PR);
    cvec_kernel<<<1, 256, 0, stream>>>(W_hopi, b_hopi, part, cvec);
    dim3 g3(64, 64);
    conv_kernel<<<g3, 512, 0, stream>>>(PL, PR, cvec, w1, b1, w2, b2, w3, b3, outp);
}

// Round 7
// 247.878 us; speedup vs baseline: 1.6830x; 1.6830x over previous
//
#include <hip/hip_runtime.h>

// All tensors float32. Math structure exploited:
//  - softmax over axis of size 1 == 1.0 -> attn all-ones, Wa/ba dead.
//  - weighted = row-sum of tanh(agg), broadcast over COLUMNS (N==D quirk).
//  - lig_p = nf@Wl.T + const  ->  x0[h,i,j] = PL[i,h] + PR[j,h] + c[h]
//  - conv1/2/3 fully fused, x0 generated on the fly (no 128MB tensor).
//  - gnn GEMM and convs on f16 MFMA, f32 accumulate.
//  - conv LDS ALIASED (weights live in dead phases of xs/ys buffers):
//    46,336 B -> 3 blocks/CU.
//  - ROUND-6 LESSON: __launch_bounds__(512,6) forced VGPR=40 -> register
//    spill to scratch -> 1.4 GB HBM traffic/dispatch. NEVER cap registers
//    here; plain (512) gives ~60-76 VGPR, no spill, same occupancy.

typedef _Float16 half8 __attribute__((ext_vector_type(8)));
typedef _Float16 half4 __attribute__((ext_vector_type(4)));
typedef float    f32x4 __attribute__((ext_vector_type(4)));

__device__ __forceinline__ short f2h_bits(float f){
    _Float16 h = (_Float16)f;          // RNE
    return __builtin_bit_cast(short, h);
}
__device__ __forceinline__ half8 pack2(const float4& x, const float4& y){
    half8 r;
    r[0] = (_Float16)x.x; r[1] = (_Float16)x.y;
    r[2] = (_Float16)x.z; r[3] = (_Float16)x.w;
    r[4] = (_Float16)y.x; r[5] = (_Float16)y.y;
    r[6] = (_Float16)y.z; r[7] = (_Float16)y.w;
    return r;
}
__device__ __forceinline__ half4 pack4(const float4& x){
    half4 r;
    r[0] = (_Float16)x.x; r[1] = (_Float16)x.y;
    r[2] = (_Float16)x.z; r[3] = (_Float16)x.w;
    return r;
}

// ci-block swizzle for conv LDS tiles (round-4 verified layout)
#define SWZ(c) ((((c) >> 1) & 3) << 3)

// ---------------------------------------------------------------------------
// K1 (MFMA): agg = tanh([nf|ef]@[Wn|We].T + bn + be); per-block row-sums over
// its 64 d-columns -> part[cx][dblk][row]. BM=BN=64, BK=64, 256 thr (4 waves,
// wave-tile 32x32), grid (16,16,2). LDS tiles f16, granule XOR swizzle.
// ---------------------------------------------------------------------------
__global__ __launch_bounds__(256) void gnn_kernel(
    const float* __restrict__ lig_nf, const float* __restrict__ lig_ef,
    const float* __restrict__ rec_nf, const float* __restrict__ rec_ef,
    const float* __restrict__ Wn, const float* __restrict__ We,
    const float* __restrict__ bn, const float* __restrict__ be,
    float* __restrict__ part)   // [2][16][1024]
{
    __shared__ __attribute__((aligned(16))) short As[64 * 64];
    __shared__ __attribute__((aligned(16))) short Bs[64 * 64];
    __shared__ float red[64][2];

    const int t  = threadIdx.x;
    const int cx = blockIdx.z;
    const float* A0 = cx ? rec_nf : lig_nf;
    const float* A1 = cx ? rec_ef : lig_ef;
    const int j0 = blockIdx.x * 64;
    const int d0 = blockIdx.y * 64;

    const int wid  = t >> 6;
    const int wm   = wid >> 1, wn = wid & 1;
    const int lane = t & 63;
    const int lr   = lane & 15;   // A: row, B: col, C: col
    const int lg   = lane >> 4;   // k-granule / C row group

    f32x4 acc[2][2];
    #pragma unroll
    for (int m = 0; m < 2; ++m)
        #pragma unroll
        for (int n = 0; n < 2; ++n)
            acc[m][n] = (f32x4){0.f, 0.f, 0.f, 0.f};

    const int srow   = t >> 2;    // staging row 0..63
    const int schunk = t & 3;     // 16-float chunk of the 64-wide K slab
    const int sswz   = srow & 7;

    for (int kb = 0; kb < 2048; kb += 64){
        const float* Asrc = (kb < 1024) ? A0 : A1;
        const float* Bsrc = (kb < 1024) ? Wn : We;
        const int kcol = (kb & 1023) + schunk * 16;
        float4 av[4], bv[4];
        const float* ap = Asrc + (size_t)(j0 + srow) * 1024 + kcol;
        const float* bp = Bsrc + (size_t)(d0 + srow) * 1024 + kcol;
        #pragma unroll
        for (int q = 0; q < 4; ++q){
            av[q] = *reinterpret_cast<const float4*>(ap + q * 4);
            bv[q] = *reinterpret_cast<const float4*>(bp + q * 4);
        }
        __syncthreads();   // previous iter's LDS reads done
        const int g0 = ((schunk * 2)     ^ sswz) * 8;
        const int g1 = ((schunk * 2 + 1) ^ sswz) * 8;
        *reinterpret_cast<half8*>(&As[srow * 64 + g0]) = pack2(av[0], av[1]);
        *reinterpret_cast<half8*>(&As[srow * 64 + g1]) = pack2(av[2], av[3]);
        *reinterpret_cast<half8*>(&Bs[srow * 64 + g0]) = pack2(bv[0], bv[1]);
        *reinterpret_cast<half8*>(&Bs[srow * 64 + g1]) = pack2(bv[2], bv[3]);
        __syncthreads();

        #pragma unroll
        for (int ks = 0; ks < 2; ++ks){
            half8 Af[2], Bf[2];
            #pragma unroll
            for (int m = 0; m < 2; ++m){
                int row = wm * 32 + m * 16 + lr;
                int g   = ((ks * 4 + lg) ^ (row & 7)) * 8;
                Af[m] = *reinterpret_cast<const half8*>(&As[row * 64 + g]);
            }
            #pragma unroll
            for (int n = 0; n < 2; ++n){
                int col = wn * 32 + n * 16 + lr;
                int g   = ((ks * 4 + lg) ^ (col & 7)) * 8;
                Bf[n] = *reinterpret_cast<const half8*>(&Bs[col * 64 + g]);
            }
            #pragma unroll
            for (int m = 0; m < 2; ++m)
                #pragma unroll
                for (int n = 0; n < 2; ++n)
                    acc[m][n] = __builtin_amdgcn_mfma_f32_16x16x32_f16(
                        Af[m], Bf[n], acc[m][n], 0, 0, 0);
        }
    }

    // epilogue: bias + tanh + reduce over the block's 64 d-columns
    float rowsum[2][4];
    #pragma unroll
    for (int m = 0; m < 2; ++m)
        #pragma unroll
        for (int jj = 0; jj < 4; ++jj) rowsum[m][jj] = 0.f;
    #pragma unroll
    for (int n = 0; n < 2; ++n){
        int d = d0 + wn * 32 + n * 16 + lr;
        float bias = bn[d] + be[d];
        #pragma unroll
        for (int m = 0; m < 2; ++m)
            #pragma unroll
            for (int jj = 0; jj < 4; ++jj)
                rowsum[m][jj] += tanhf(acc[m][n][jj] + bias);
    }
    #pragma unroll
    for (int mask = 1; mask < 16; mask <<= 1)
        #pragma unroll
        for (int m = 0; m < 2; ++m)
            #pragma unroll
            for (int jj = 0; jj < 4; ++jj)
                rowsum[m][jj] += __shfl_xor(rowsum[m][jj], mask);
    __syncthreads();
    if (lr == 0){
        #pragma unroll
        for (int m = 0; m < 2; ++m)
            #pragma unroll
            for (int jj = 0; jj < 4; ++jj)
                red[wm * 32 + m * 16 + lg * 4 + jj][wn] = rowsum[m][jj];
    }
    __syncthreads();
    if (t < 64)
        part[(size_t)cx * 16384 + (size_t)blockIdx.y * 1024 + j0 + t]
            = red[t][0] + red[t][1];
}

// ---------------------------------------------------------------------------
// K2a: PL[i,h] = sum_j nf[i,j]*Wl[h,j]; PR analog. grid (128,2), block 256
// ---------------------------------------------------------------------------
__global__ __launch_bounds__(256) void proj_kernel(
    const float* __restrict__ lig_nf, const float* __restrict__ rec_nf,
    const float* __restrict__ W_hopi, float* __restrict__ PL, float* __restrict__ PR)
{
    const int t  = threadIdx.x;
    const int cx = blockIdx.y;
    const float* nf = cx ? rec_nf : lig_nf;
    const float* W  = W_hopi + (cx ? 1024 : 0);
    float* outp     = cx ? PR : PL;
    const int h = t & 31;
    const int i = blockIdx.x * 8 + (t >> 5);
    const float* nrow = nf + (size_t)i * 1024;
    const float* wrow = W + (size_t)h * 2048;
    float s0 = 0.f, s1 = 0.f;
    #pragma unroll 4
    for (int j = 0; j < 1024; j += 8){
        float4 a0 = *reinterpret_cast<const float4*>(nrow + j);
        float4 b0 = *reinterpret_cast<const float4*>(wrow + j);
        float4 a1 = *reinterpret_cast<const float4*>(nrow + j + 4);
        float4 b1 = *reinterpret_cast<const float4*>(wrow + j + 4);
        s0 = fmaf(a0.x, b0.x, s0); s0 = fmaf(a0.y, b0.y, s0);
        s0 = fmaf(a0.z, b0.z, s0); s0 = fmaf(a0.w, b0.w, s0);
        s1 = fmaf(a1.x, b1.x, s1); s1 = fmaf(a1.y, b1.y, s1);
        s1 = fmaf(a1.z, b1.z, s1); s1 = fmaf(a1.w, b1.w, s1);
    }
    outp[(size_t)i * 32 + h] = s0 + s1;
}

// ---------------------------------------------------------------------------
// K2b: w[j] = block-sum of part; c[h] = b_hopi[h] + wL.Wl[h] + wR.Wr[h]
// ---------------------------------------------------------------------------
__global__ __launch_bounds__(256) void cvec_kernel(
    const float* __restrict__ W_hopi, const float* __restrict__ b_hopi,
    const float* __restrict__ part, float* __restrict__ cvec)
{
    __shared__ float ws_l[1024];
    __shared__ float ws_r[1024];
    __shared__ float red[256];
    const int t = threadIdx.x;
    for (int j = t; j < 1024; j += 256){
        float sl = 0.f, sr = 0.f;
        #pragma unroll
        for (int b = 0; b < 16; ++b){
            sl += part[b * 1024 + j];
            sr += part[16384 + b * 1024 + j];
        }
        ws_l[j] = sl; ws_r[j] = sr;
    }
    __syncthreads();
    const int h = t & 31;
    const int seg = t >> 5;
    float s = 0.f;
    for (int j = seg * 128; j < seg * 128 + 128; ++j){
        s = fmaf(ws_l[j], W_hopi[(size_t)h * 2048 + j], s);
        s = fmaf(ws_r[j], W_hopi[(size_t)h * 2048 + 1024 + j], s);
    }
    red[t] = s;
    __syncthreads();
    if (t < 32){
        float tot = b_hopi[t];
        #pragma unroll
        for (int g = 0; g < 8; ++g) tot += red[g * 32 + t];
        cvec[t] = tot;
    }
}

// ---------------------------------------------------------------------------
// K3: fused conv1+relu -> conv2+relu -> conv3 on f16 MFMA (round-4 layout).
// LDS aliasing: wB1 lives in ysbuf (dead until Bf1 hoisted to regs);
// wB2 restaged into xsbuf (dead after conv1). Total 46,336 B -> 3 blocks/CU.
// block 512 (8 waves), grid 64x64. NO register cap (round-6 spill lesson).
// ---------------------------------------------------------------------------
__global__ __launch_bounds__(512) void conv_kernel(
    const float* __restrict__ PL, const float* __restrict__ PR,
    const float* __restrict__ cvec,
    const float* __restrict__ w1, const float* __restrict__ b1,
    const float* __restrict__ w2, const float* __restrict__ b2,
    const float* __restrict__ w3, const float* __restrict__ b3,
    float* __restrict__ outp)
{
    __shared__ __attribute__((aligned(16))) short xsbuf[20 * 20 * 32]; // 25600 B; later wB2
    __shared__ __attribute__((aligned(16))) short ysbuf[18 * 18 * 32]; // 20736 B; first wB1

    short* xs  = xsbuf;
    short* ys  = ysbuf;
    short* wB1 = ysbuf;    // 9216 shorts <= 10368
    short* wB2 = xsbuf;    // 9216 shorts <= 12800

    const int t    = threadIdx.x;
    const int oy0  = blockIdx.y * 16;
    const int ox0  = blockIdx.x * 16;
    const int wid  = t >> 6;
    const int lane = t & 63;
    const int lr   = lane & 15;
    const int lg   = lane >> 4;

    // ---- stage x0 tile: 400 pixels x 32 ci, float4 path, div-free walk ----
    {
        const int cp  = (t & 7) * 4;      // ci quad (4-aligned; SWZ keeps alignment)
        const int grp = t >> 3;           // 64 pixels per pass
        int ry = grp / 20;
        int rx = grp - ry * 20;
        #pragma unroll
        for (int pass = 0; pass < 7; ++pass){
            int pp = grp + pass * 64;
            if (pp < 400){
                int a = oy0 - 2 + ry, b = ox0 - 2 + rx;
                float4 v = make_float4(0.f, 0.f, 0.f, 0.f);
                if (a >= 0 && a < 1024 && b >= 0 && b < 1024){
                    float4 pl = *reinterpret_cast<const float4*>(PL + a * 32 + cp);
                    float4 pr = *reinterpret_cast<const float4*>(PR + b * 32 + cp);
                    float4 cv = *reinterpret_cast<const float4*>(cvec + cp);
                    v = make_float4(pl.x + pr.x + cv.x, pl.y + pr.y + cv.y,
                                    pl.z + pr.z + cv.z, pl.w + pr.w + cv.w);
                }
                *reinterpret_cast<half4*>(&xs[pp * 32 + (cp ^ SWZ(rx))]) = pack4(v);
            }
            ry += 3; rx += 4;
            if (rx >= 20){ rx -= 20; ry += 1; }
        }
    }
    // ---- stage conv1 weights into wB1 (coalesced 64B reads per 16 lanes) ----
    {
        const int co_s = t >> 4;          // 0..31
        const int ls   = t & 15;
        #pragma unroll
        for (int kk = 0; kk < 18; ++kk){
            int k   = ls + (kk << 4);     // 0..287
            int ci  = k / 9;
            int tap = k - ci * 9;
            wB1[(tap * 32 + co_s) * 32 + (ci ^ SWZ(co_s))] =
                f2h_bits(w1[co_s * 288 + k]);
        }
    }
    __syncthreads();

    // ================= conv1: 324 outputs (18x18) =========
    {
        half8 Bf[2][9];
        float bias[2];
        #pragma unroll
        for (int n = 0; n < 2; ++n){
            int co = n * 16 + lr;
            bias[n] = b1[co];
            #pragma unroll
            for (int tap = 0; tap < 9; ++tap)
                Bf[n][tap] = *reinterpret_cast<const half8*>(
                    &wB1[(tap * 32 + co) * 32 + ((lg * 8) ^ SWZ(co))]);
        }
        __syncthreads();   // all waves finished reading wB1 before ys writes

        for (int s = wid; s < 21; s += 8){
            int praw = s * 16 + lr;
            int p  = praw > 323 ? 323 : praw;
            int ry = p / 18;
            int rx = p - ry * 18;
            f32x4 acc0 = {0.f, 0.f, 0.f, 0.f};
            f32x4 acc1 = {0.f, 0.f, 0.f, 0.f};
            #pragma unroll
            for (int tap = 0; tap < 9; ++tap){
                const int dy = tap / 3, dx = tap - (tap / 3) * 3;
                int pix = (ry + dy) * 20 + rx + dx;
                half8 A = *reinterpret_cast<const half8*>(
                    &xs[pix * 32 + ((lg * 8) ^ SWZ(rx + dx))]);
                acc0 = __builtin_amdgcn_mfma_f32_16x16x32_f16(A, Bf[0][tap], acc0, 0, 0, 0);
                acc1 = __builtin_amdgcn_mfma_f32_16x16x32_f16(A, Bf[1][tap], acc1, 0, 0, 0);
            }
            // epilogue: single div + wrap-increment
            int po  = s * 16 + lg * 4;
            int ryo = po / 18;
            int rxo = po - ryo * 18;
            #pragma unroll
            for (int j = 0; j < 4; ++j){
                if (po + j < 324){
                    int gy = oy0 - 1 + ryo, gx = ox0 - 1 + rxo;
                    bool ok = (gy >= 0) & (gy < 1024) & (gx >= 0) & (gx < 1024);
                    float v0 = ok ? fmaxf(acc0[j] + bias[0], 0.f) : 0.f;
                    float v1 = ok ? fmaxf(acc1[j] + bias[1], 0.f) : 0.f;
                    int sw = SWZ(rxo);
                    ys[(po + j) * 32 + (lr ^ sw)]        = f2h_bits(v0);
                    ys[(po + j) * 32 + ((16 + lr) ^ sw)] = f2h_bits(v1);
                }
                rxo += 1;
                if (rxo == 18){ rxo = 0; ryo += 1; }
            }
        }
    }
    __syncthreads();
    // ---- stage conv2 weights into wB2 (= xsbuf, xs is dead) ----
    {
        const int co_s = t >> 4;
        const int ls   = t & 15;
        #pragma unroll
        for (int kk = 0; kk < 18; ++kk){
            int k   = ls + (kk << 4);
            int ci  = k / 9;
            int tap = k - ci * 9;
            wB2[(tap * 32 + co_s) * 32 + (ci ^ SWZ(co_s))] =
                f2h_bits(w2[co_s * 288 + k]);
        }
    }
    __syncthreads();

    // ================= conv2 + conv3: 256 outputs =========
    {
        half8 Bf[2][9];
        float bias[2], w3v[2];
        #pragma unroll
        for (int n = 0; n < 2; ++n){
            int co = n * 16 + lr;
            bias[n] = b2[co];
            w3v[n]  = w3[co];
            #pragma unroll
            for (int tap = 0; tap < 9; ++tap)
                Bf[n][tap] = *reinterpret_cast<const half8*>(
                    &wB2[(tap * 32 + co) * 32 + ((lg * 8) ^ SWZ(co))]);
        }
        const float b3v = b3[0];
        for (int s = wid; s < 16; s += 8){
            int p  = s * 16 + lr;
            int ry = p >> 4;
            int rx = p & 15;
            f32x4 acc0 = {0.f, 0.f, 0.f, 0.f};
            f32x4 acc1 = {0.f, 0.f, 0.f, 0.f};
            #pragma unroll
            for (int tap = 0; tap < 9; ++tap){
                const int dy = tap / 3, dx = tap - (tap / 3) * 3;
                int pix = (ry + dy) * 18 + rx + dx;
                half8 A = *reinterpret_cast<const half8*>(
                    &ys[pix * 32 + ((lg * 8) ^ SWZ(rx + dx))]);
                acc0 = __builtin_amdgcn_mfma_f32_16x16x32_f16(A, Bf[0][tap], acc0, 0, 0, 0);
                acc1 = __builtin_amdgcn_mfma_f32_16x16x32_f16(A, Bf[1][tap], acc1, 0, 0, 0);
            }
            float part[4];
            #pragma unroll
            for (int j = 0; j < 4; ++j)
                part[j] = w3v[0] * fmaxf(acc0[j] + bias[0], 0.f)
                        + w3v[1] * fmaxf(acc1[j] + bias[1], 0.f);
            #pragma unroll
            for (int m = 1; m < 16; m <<= 1)
                #pragma unroll
                for (int j = 0; j < 4; ++j)
                    part[j] += __shfl_xor(part[j], m);
            if (lr == 0){
                float4 o = make_float4(part[0] + b3v, part[1] + b3v,
                                       part[2] + b3v, part[3] + b3v);
                *reinterpret_cast<float4*>(outp + (size_t)(oy0 + s) * 1024 + ox0 + lg * 4) = o;
            }
        }
    }
}

// ---------------------------------------------------------------------------
extern "C" void kernel_launch(void* const* d_in, const int* in_sizes, int n_in,
                              void* d_out, int out_size, void* d_ws, size_t ws_size,
                              hipStream_t stream)
{
    const float* lig_nf = (const float*)d_in[0];
    const float* lig_ef = (const float*)d_in[1];
    const float* rec_nf = (const float*)d_in[3];
    const float* rec_ef = (const float*)d_in[4];
    const float* Wn     = (const float*)d_in[6];
    const float* bn     = (const float*)d_in[7];
    const float* We     = (const float*)d_in[8];
    const float* be     = (const float*)d_in[9];
    const float* W_hopi = (const float*)d_in[12];
    const float* b_hopi = (const float*)d_in[13];
    const float* w1     = (const float*)d_in[14];
    const float* b1     = (const float*)d_in[15];
    const float* w2     = (const float*)d_in[16];
    const float* b2     = (const float*)d_in[17];
    const float* w3     = (const float*)d_in[18];
    const float* b3     = (const float*)d_in[19];
    float* outp = (float*)d_out;

    float* part = (float*)d_ws;                               // [2][16][1024]
    float* PL   = (float*)((char*)d_ws + 131072);
    float* PR   = (float*)((char*)d_ws + 262144);
    float* cvec = (float*)((char*)d_ws + 393216);

    dim3 g1(16, 16, 2);
    gnn_kernel<<<g1, 256, 0, stream>>>(lig_nf, lig_ef, rec_nf, rec_ef,
                                       Wn, We, bn, be, part);
    dim3 g2(128, 2);
    proj_kernel<<<g2, 256, 0, stream>>>(lig_nf, rec_nf, W_hopi, PL, PR);
    cvec_kernel<<<1, 256, 0, stream>>>(W_hopi, b_hopi, part, cvec);
    dim3 g3(64, 64);
    conv_kernel<<<g3, 512, 0, stream>>>(PL, PR, cvec, w1, b1, w2, b2, w3, b3, outp);
}

// Round 8
// 222.680 us; speedup vs baseline: 1.8734x; 1.1132x over previous
//
#include <hip/hip_runtime.h>

// All tensors float32. Math structure exploited:
//  - softmax over axis of size 1 == 1.0 -> attn all-ones, Wa/ba dead.
//  - weighted = row-sum of tanh(agg), broadcast over COLUMNS (N==D quirk).
//  - lig_p = nf@Wl.T + const  ->  x0[h,i,j] = PL[i,h] + PR[j,h] + c[h]
//  - conv1/2/3 fully fused, x0 generated on the fly (no 128MB tensor).
//  - gnn GEMM and convs on f16 MFMA, f32 accumulate.
//  - conv kernel = EXACT round-4 version (131.7 us proven; rounds 5-7
//    restructures all regressed: granule-major -> LDS 64K occupancy cliff;
//    launch_bounds(512,6) -> VGPR-40 spill, 1.4 GB scratch traffic;
//    aliasing+extra barrier -> idle-bound 148 us).
//  - gnn now: BM=128/BN=64, 8 waves, REGISTER PREFETCH of next K-slab so HBM
//    latency hides under MFMA (it was latency-bound at ~60 us), fast tanh.

typedef _Float16 half8 __attribute__((ext_vector_type(8)));
typedef float    f32x4 __attribute__((ext_vector_type(4)));

__device__ __forceinline__ short f2h_bits(float f){
    _Float16 h = (_Float16)f;          // RNE
    return __builtin_bit_cast(short, h);
}
__device__ __forceinline__ half8 pack2(const float4& x, const float4& y){
    half8 r;
    r[0] = (_Float16)x.x; r[1] = (_Float16)x.y;
    r[2] = (_Float16)x.z; r[3] = (_Float16)x.w;
    r[4] = (_Float16)y.x; r[5] = (_Float16)y.y;
    r[6] = (_Float16)y.z; r[7] = (_Float16)y.w;
    return r;
}
__device__ __forceinline__ float tanh_fast(float x){
    float e = __expf(2.f * x);
    return 1.f - 2.f / (e + 1.f);
}

// ci-block swizzle for conv LDS tiles (round-4 verified layout)
#define SWZ(c) ((((c) >> 1) & 3) << 3)

// ---------------------------------------------------------------------------
// K1 (MFMA): agg = tanh([nf|ef]@[Wn|We].T + bn + be); per-block row-sums over
// its 64 d-columns -> part[cx][dblk][row]. BM=128, BN=64, BK=64, 512 thr
// (8 waves, 4x2 grid of 32x32 wave-tiles), grid (8,16,2) = 1 block/CU.
// Register prefetch: next K-slab's global loads issue right after LDS write,
// in flight during the MFMA phase.
// ---------------------------------------------------------------------------
__global__ __launch_bounds__(512) void gnn_kernel(
    const float* __restrict__ lig_nf, const float* __restrict__ lig_ef,
    const float* __restrict__ rec_nf, const float* __restrict__ rec_ef,
    const float* __restrict__ Wn, const float* __restrict__ We,
    const float* __restrict__ bn, const float* __restrict__ be,
    float* __restrict__ part)   // [2][16][1024]
{
    __shared__ __attribute__((aligned(16))) short As[128 * 64];
    __shared__ __attribute__((aligned(16))) short Bs[64 * 64];
    __shared__ float red[128][2];

    const int t  = threadIdx.x;
    const int cx = blockIdx.z;
    const float* A0 = cx ? rec_nf : lig_nf;
    const float* A1 = cx ? rec_ef : lig_ef;
    const int j0 = blockIdx.x * 128;
    const int d0 = blockIdx.y * 64;

    const int wid  = t >> 6;
    const int wm   = wid >> 1;       // 0..3 (M wave-tile)
    const int wn   = wid & 1;        // 0..1 (N wave-tile)
    const int lane = t & 63;
    const int lr   = lane & 15;      // A: row, B: col, C: col
    const int lg   = lane >> 4;      // k-granule / C row group

    f32x4 acc[2][2];
    #pragma unroll
    for (int m = 0; m < 2; ++m)
        #pragma unroll
        for (int n = 0; n < 2; ++n)
            acc[m][n] = (f32x4){0.f, 0.f, 0.f, 0.f};

    // staging assignment: A 128 rows x 64k -> 16 floats/thread;
    //                     B  64 rows x 64k ->  8 floats/thread
    const int arow = t >> 2;             // 0..127
    const int akc  = (t & 3) * 16;       // k offset within slab
    const int brow = t >> 3;             // 0..63
    const int bkc  = (t & 7) * 8;

    float4 av[4], bv[2];
    {   // preload slab kb=0 (Asrc=A0, Bsrc=Wn)
        const float* ap = A0 + (size_t)(j0 + arow) * 1024 + akc;
        const float* bp = Wn + (size_t)(d0 + brow) * 1024 + bkc;
        #pragma unroll
        for (int q = 0; q < 4; ++q) av[q] = *reinterpret_cast<const float4*>(ap + q * 4);
        #pragma unroll
        for (int q = 0; q < 2; ++q) bv[q] = *reinterpret_cast<const float4*>(bp + q * 4);
    }

    for (int kb = 0; kb < 2048; kb += 64){
        __syncthreads();   // previous iter's LDS reads done
        {   // stage current slab from prefetched regs (granule XOR swizzle)
            const int ga = (t & 3) * 2;
            const int sa = arow & 7;
            *reinterpret_cast<half8*>(&As[arow * 64 + ((ga    ) ^ sa) * 8]) = pack2(av[0], av[1]);
            *reinterpret_cast<half8*>(&As[arow * 64 + ((ga + 1) ^ sa) * 8]) = pack2(av[2], av[3]);
            *reinterpret_cast<half8*>(&Bs[brow * 64 + (((t & 7)) ^ (brow & 7)) * 8]) = pack2(bv[0], bv[1]);
        }
        {   // prefetch next slab (wraps harmlessly on last iter)
            const int kbn = (kb + 64) & 2047;
            const float* Asrc = (kbn < 1024) ? A0 : A1;
            const float* Bsrc = (kbn < 1024) ? Wn : We;
            const int kk = kbn & 1023;
            const float* ap = Asrc + (size_t)(j0 + arow) * 1024 + kk + akc;
            const float* bp = Bsrc + (size_t)(d0 + brow) * 1024 + kk + bkc;
            #pragma unroll
            for (int q = 0; q < 4; ++q) av[q] = *reinterpret_cast<const float4*>(ap + q * 4);
            #pragma unroll
            for (int q = 0; q < 2; ++q) bv[q] = *reinterpret_cast<const float4*>(bp + q * 4);
        }
        __syncthreads();   // LDS slab ready

        #pragma unroll
        for (int ks = 0; ks < 2; ++ks){
            half8 Af[2], Bf[2];
            #pragma unroll
            for (int m = 0; m < 2; ++m){
                int row = wm * 32 + m * 16 + lr;
                int g   = ((ks * 4 + lg) ^ (row & 7)) * 8;
                Af[m] = *reinterpret_cast<const half8*>(&As[row * 64 + g]);
            }
            #pragma unroll
            for (int n = 0; n < 2; ++n){
                int col = wn * 32 + n * 16 + lr;
                int g   = ((ks * 4 + lg) ^ (col & 7)) * 8;
                Bf[n] = *reinterpret_cast<const half8*>(&Bs[col * 64 + g]);
            }
            #pragma unroll
            for (int m = 0; m < 2; ++m)
                #pragma unroll
                for (int n = 0; n < 2; ++n)
                    acc[m][n] = __builtin_amdgcn_mfma_f32_16x16x32_f16(
                        Af[m], Bf[n], acc[m][n], 0, 0, 0);
        }
    }

    // epilogue: bias + tanh + reduce over the block's 64 d-columns
    float rowsum[2][4];
    #pragma unroll
    for (int m = 0; m < 2; ++m)
        #pragma unroll
        for (int jj = 0; jj < 4; ++jj) rowsum[m][jj] = 0.f;
    #pragma unroll
    for (int n = 0; n < 2; ++n){
        int d = d0 + wn * 32 + n * 16 + lr;
        float bias = bn[d] + be[d];
        #pragma unroll
        for (int m = 0; m < 2; ++m)
            #pragma unroll
            for (int jj = 0; jj < 4; ++jj)
                rowsum[m][jj] += tanh_fast(acc[m][n][jj] + bias);
    }
    #pragma unroll
    for (int mask = 1; mask < 16; mask <<= 1)
        #pragma unroll
        for (int m = 0; m < 2; ++m)
            #pragma unroll
            for (int jj = 0; jj < 4; ++jj)
                rowsum[m][jj] += __shfl_xor(rowsum[m][jj], mask);
    __syncthreads();
    if (lr == 0){
        #pragma unroll
        for (int m = 0; m < 2; ++m)
            #pragma unroll
            for (int jj = 0; jj < 4; ++jj)
                red[wm * 32 + m * 16 + lg * 4 + jj][wn] = rowsum[m][jj];
    }
    __syncthreads();
    if (t < 128)
        part[(size_t)cx * 16384 + (size_t)blockIdx.y * 1024 + j0 + t]
            = red[t][0] + red[t][1];
}

// ---------------------------------------------------------------------------
// K2a: PL[i,h] = sum_j nf[i,j]*Wl[h,j]; PR analog. grid (128,2), block 256
// ---------------------------------------------------------------------------
__global__ __launch_bounds__(256) void proj_kernel(
    const float* __restrict__ lig_nf, const float* __restrict__ rec_nf,
    const float* __restrict__ W_hopi, float* __restrict__ PL, float* __restrict__ PR)
{
    const int t  = threadIdx.x;
    const int cx = blockIdx.y;
    const float* nf = cx ? rec_nf : lig_nf;
    const float* W  = W_hopi + (cx ? 1024 : 0);
    float* outp     = cx ? PR : PL;
    const int h = t & 31;
    const int i = blockIdx.x * 8 + (t >> 5);
    const float* nrow = nf + (size_t)i * 1024;
    const float* wrow = W + (size_t)h * 2048;
    float s0 = 0.f, s1 = 0.f;
    #pragma unroll 4
    for (int j = 0; j < 1024; j += 8){
        float4 a0 = *reinterpret_cast<const float4*>(nrow + j);
        float4 b0 = *reinterpret_cast<const float4*>(wrow + j);
        float4 a1 = *reinterpret_cast<const float4*>(nrow + j + 4);
        float4 b1 = *reinterpret_cast<const float4*>(wrow + j + 4);
        s0 = fmaf(a0.x, b0.x, s0); s0 = fmaf(a0.y, b0.y, s0);
        s0 = fmaf(a0.z, b0.z, s0); s0 = fmaf(a0.w, b0.w, s0);
        s1 = fmaf(a1.x, b1.x, s1); s1 = fmaf(a1.y, b1.y, s1);
        s1 = fmaf(a1.z, b1.z, s1); s1 = fmaf(a1.w, b1.w, s1);
    }
    outp[(size_t)i * 32 + h] = s0 + s1;
}

// ---------------------------------------------------------------------------
// K2b: w[j] = block-sum of part; c[h] = b_hopi[h] + wL.Wl[h] + wR.Wr[h]
// ---------------------------------------------------------------------------
__global__ __launch_bounds__(256) void cvec_kernel(
    const float* __restrict__ W_hopi, const float* __restrict__ b_hopi,
    const float* __restrict__ part, float* __restrict__ cvec)
{
    __shared__ float ws_l[1024];
    __shared__ float ws_r[1024];
    __shared__ float red[256];
    const int t = threadIdx.x;
    for (int j = t; j < 1024; j += 256){
        float sl = 0.f, sr = 0.f;
        #pragma unroll
        for (int b = 0; b < 16; ++b){
            sl += part[b * 1024 + j];
            sr += part[16384 + b * 1024 + j];
        }
        ws_l[j] = sl; ws_r[j] = sr;
    }
    __syncthreads();
    const int h = t & 31;
    const int seg = t >> 5;
    float s = 0.f;
    for (int j = seg * 128; j < seg * 128 + 128; ++j){
        s = fmaf(ws_l[j], W_hopi[(size_t)h * 2048 + j], s);
        s = fmaf(ws_r[j], W_hopi[(size_t)h * 2048 + 1024 + j], s);
    }
    red[t] = s;
    __syncthreads();
    if (t < 32){
        float tot = b_hopi[t];
        #pragma unroll
        for (int g = 0; g < 8; ++g) tot += red[g * 32 + t];
        cvec[t] = tot;
    }
}

// ---------------------------------------------------------------------------
// K3: fused conv1+relu -> conv2+relu -> conv3 on f16 MFMA.
// EXACT round-4 kernel (131.7 us, VGPR 60, LDS 65024, 2 blocks/CU).
// ---------------------------------------------------------------------------
__global__ __launch_bounds__(512) void conv_kernel(
    const float* __restrict__ PL, const float* __restrict__ PR,
    const float* __restrict__ cvec,
    const float* __restrict__ w1, const float* __restrict__ b1,
    const float* __restrict__ w2, const float* __restrict__ b2,
    const float* __restrict__ w3, const float* __restrict__ b3,
    float* __restrict__ outp)
{
    __shared__ __attribute__((aligned(16))) short xs[20 * 20 * 32];
    __shared__ __attribute__((aligned(16))) short ys[18 * 18 * 32];
    __shared__ __attribute__((aligned(16))) short wB[9 * 32 * 32];

    const int t    = threadIdx.x;
    const int oy0  = blockIdx.y * 16;
    const int ox0  = blockIdx.x * 16;
    const int wid  = t >> 6;
    const int lane = t & 63;
    const int lr   = lane & 15;
    const int lg   = lane >> 4;

    // ---- stage x0 tile: 400 pixels x 32 ci ----
    {
        const int grp = t >> 4;
        const int cp  = (t & 15) * 2;
        #pragma unroll
        for (int pass = 0; pass < 13; ++pass){
            int pp = grp + pass * 32;
            if (pp < 400){
                int ry = pp / 20, rx = pp - ry * 20;
                int a = oy0 - 2 + ry, b = ox0 - 2 + rx;
                float v0 = 0.f, v1 = 0.f;
                if (a >= 0 && a < 1024 && b >= 0 && b < 1024){
                    float2 pl = *reinterpret_cast<const float2*>(PL + a * 32 + cp);
                    float2 pr = *reinterpret_cast<const float2*>(PR + b * 32 + cp);
                    float2 cv = *reinterpret_cast<const float2*>(cvec + cp);
                    v0 = pl.x + pr.x + cv.x;
                    v1 = pl.y + pr.y + cv.y;
                }
                int addr = pp * 32 + (cp ^ SWZ(rx));
                *reinterpret_cast<short2*>(&xs[addr]) =
                    make_short2(f2h_bits(v0), f2h_bits(v1));
            }
        }
    }
    for (int e = t; e < 9216; e += 512){
        int co  = e / 288;
        int rem = e - co * 288;
        int ci  = rem / 9;
        int tap = rem - ci * 9;
        wB[(tap * 32 + co) * 32 + (ci ^ SWZ(co))] = f2h_bits(w1[e]);
    }
    __syncthreads();

    // ================= conv1: 324 outputs (18x18) =========
    {
        half8 Bf[2][9];
        float bias[2];
        #pragma unroll
        for (int n = 0; n < 2; ++n){
            int co = n * 16 + lr;
            bias[n] = b1[co];
            #pragma unroll
            for (int tap = 0; tap < 9; ++tap)
                Bf[n][tap] = *reinterpret_cast<const half8*>(
                    &wB[(tap * 32 + co) * 32 + ((lg * 8) ^ SWZ(co))]);
        }
        for (int s = wid; s < 21; s += 8){
            int praw = s * 16 + lr;
            int p  = praw > 323 ? 323 : praw;
            int ry = p / 18;
            int rx = p - ry * 18;
            f32x4 acc0 = {0.f, 0.f, 0.f, 0.f};
            f32x4 acc1 = {0.f, 0.f, 0.f, 0.f};
            #pragma unroll
            for (int tap = 0; tap < 9; ++tap){
                const int dy = tap / 3, dx = tap - (tap / 3) * 3;
                int pix = (ry + dy) * 20 + rx + dx;
                half8 A = *reinterpret_cast<const half8*>(
                    &xs[pix * 32 + ((lg * 8) ^ SWZ(rx + dx))]);
                acc0 = __builtin_amdgcn_mfma_f32_16x16x32_f16(A, Bf[0][tap], acc0, 0, 0, 0);
                acc1 = __builtin_amdgcn_mfma_f32_16x16x32_f16(A, Bf[1][tap], acc1, 0, 0, 0);
            }
            #pragma unroll
            for (int j = 0; j < 4; ++j){
                int po = s * 16 + lg * 4 + j;
                if (po < 324){
                    int ryo = po / 18;
                    int rxo = po - ryo * 18;
                    int gy = oy0 - 1 + ryo, gx = ox0 - 1 + rxo;
                    bool ok = (gy >= 0) & (gy < 1024) & (gx >= 0) & (gx < 1024);
                    float v0 = ok ? fmaxf(acc0[j] + bias[0], 0.f) : 0.f;
                    float v1 = ok ? fmaxf(acc1[j] + bias[1], 0.f) : 0.f;
                    int sw = SWZ(rxo);
                    ys[po * 32 + (lr ^ sw)]        = f2h_bits(v0);
                    ys[po * 32 + ((16 + lr) ^ sw)] = f2h_bits(v1);
                }
            }
        }
    }
    __syncthreads();
    for (int e = t; e < 9216; e += 512){
        int co  = e / 288;
        int rem = e - co * 288;
        int ci  = rem / 9;
        int tap = rem - ci * 9;
        wB[(tap * 32 + co) * 32 + (ci ^ SWZ(co))] = f2h_bits(w2[e]);
    }
    __syncthreads();

    // ================= conv2 + conv3: 256 outputs =========
    {
        half8 Bf[2][9];
        float bias[2], w3v[2];
        #pragma unroll
        for (int n = 0; n < 2; ++n){
            int co = n * 16 + lr;
            bias[n] = b2[co];
            w3v[n]  = w3[co];
            #pragma unroll
            for (int tap = 0; tap < 9; ++tap)
                Bf[n][tap] = *reinterpret_cast<const half8*>(
                    &wB[(tap * 32 + co) * 32 + ((lg * 8) ^ SWZ(co))]);
        }
        const float b3v = b3[0];
        for (int s = wid; s < 16; s += 8){
            int p  = s * 16 + lr;
            int ry = p >> 4;
            int rx = p & 15;
            f32x4 acc0 = {0.f, 0.f, 0.f, 0.f};
            f32x4 acc1 = {0.f, 0.f, 0.f, 0.f};
            #pragma unroll
            for (int tap = 0; tap < 9; ++tap){
                const int dy = tap / 3, dx = tap - (tap / 3) * 3;
                int pix = (ry + dy) * 18 + rx + dx;
                half8 A = *reinterpret_cast<const half8*>(
                    &ys[pix * 32 + ((lg * 8) ^ SWZ(rx + dx))]);
                acc0 = __builtin_amdgcn_mfma_f32_16x16x32_f16(A, Bf[0][tap], acc0, 0, 0, 0);
                acc1 = __builtin_amdgcn_mfma_f32_16x16x32_f16(A, Bf[1][tap], acc1, 0, 0, 0);
            }
            float part[4];
            #pragma unroll
            for (int j = 0; j < 4; ++j)
                part[j] = w3v[0] * fmaxf(acc0[j] + bias[0], 0.f)
                        + w3v[1] * fmaxf(acc1[j] + bias[1], 0.f);
            #pragma unroll
            for (int m = 1; m < 16; m <<= 1)
                #pragma unroll
                for (int j = 0; j < 4; ++j)
                    part[j] += __shfl_xor(part[j], m);
            if (lr == 0){
                float4 o = make_float4(part[0] + b3v, part[1] + b3v,
                                       part[2] + b3v, part[3] + b3v);
                *reinterpret_cast<float4*>(outp + (size_t)(oy0 + s) * 1024 + ox0 + lg * 4) = o;
            }
        }
    }
}

// ---------------------------------------------------------------------------
extern "C" void kernel_launch(void* const* d_in, const int* in_sizes, int n_in,
                              void* d_out, int out_size, void* d_ws, size_t ws_size,
                              hipStream_t stream)
{
    const float* lig_nf = (const float*)d_in[0];
    const float* lig_ef = (const float*)d_in[1];
    const float* rec_nf = (const float*)d_in[3];
    const float* rec_ef = (const float*)d_in[4];
    const float* Wn     = (const float*)d_in[6];
    const float* bn     = (const float*)d_in[7];
    const float* We     = (const float*)d_in[8];
    const float* be     = (const float*)d_in[9];
    const float* W_hopi = (const float*)d_in[12];
    const float* b_hopi = (const float*)d_in[13];
    const float* w1     = (const float*)d_in[14];
    const float* b1     = (const float*)d_in[15];
    const float* w2     = (const float*)d_in[16];
    const float* b2     = (const float*)d_in[17];
    const float* w3     = (const float*)d_in[18];
    const float* b3     = (const float*)d_in[19];
    float* outp = (float*)d_out;

    float* part = (float*)d_ws;                               // [2][16][1024]
    float* PL   = (float*)((char*)d_ws + 131072);
    float* PR   = (float*)((char*)d_ws + 262144);
    float* cvec = (float*)((char*)d_ws + 393216);

    dim3 g1(8, 16, 2);
    gnn_kernel<<<g1, 512, 0, stream>>>(lig_nf, lig_ef, rec_nf, rec_ef,
                                       Wn, We, bn, be, part);
    dim3 g2(128, 2);
    proj_kernel<<<g2, 256, 0, stream>>>(lig_nf, rec_nf, W_hopi, PL, PR);
    cvec_kernel<<<1, 256, 0, stream>>>(W_hopi, b_hopi, part, cvec);
    dim3 g3(64, 64);
    conv_kernel<<<g3, 512, 0, stream>>>(PL, PR, cvec, w1, b1, w2, b2, w3, b3, outp);
}

// Round 9
// 222.491 us; speedup vs baseline: 1.8750x; 1.0008x over previous
//
#include <hip/hip_runtime.h>

// All tensors float32. Math structure exploited:
//  - softmax over axis of size 1 == 1.0 -> attn all-ones, Wa/ba dead.
//  - weighted = row-sum of tanh(agg), broadcast over COLUMNS (N==D quirk).
//  - lig_p = nf@Wl.T + const  ->  x0[h,i,j] = PL[i,h] + PR[j,h] + c[h]
//  - NEW (round 9): conv1 is LINEAR in the rank-structured x0, so
//      y1_pre[co,y,x] = U[xcase][co,y] + V[ycase][co,x] + K'[ycase][xcase][co]
//    with U = 1D conv of PL over y (K=96), V = 1D conv of PR over x, and
//    border cases (SAME pad) factorized exactly into 3x3 tap-subset variants.
//    conv kernel stages ys = relu(U+V+K') directly: conv1's MFMA work,
//    x0 staging, and one weight restage are deleted. conv2+conv3 = round-4
//    verbatim (proven layout/swizzle). LDS 65024 -> 39168 B.
//  - gnn GEMM on f16 MFMA with register prefetch (round-8 version).

typedef _Float16 half8 __attribute__((ext_vector_type(8)));
typedef _Float16 half4 __attribute__((ext_vector_type(4)));
typedef float    f32x4 __attribute__((ext_vector_type(4)));

__device__ __forceinline__ short f2h_bits(float f){
    _Float16 h = (_Float16)f;          // RNE
    return __builtin_bit_cast(short, h);
}
__device__ __forceinline__ half8 pack2(const float4& x, const float4& y){
    half8 r;
    r[0] = (_Float16)x.x; r[1] = (_Float16)x.y;
    r[2] = (_Float16)x.z; r[3] = (_Float16)x.w;
    r[4] = (_Float16)y.x; r[5] = (_Float16)y.y;
    r[6] = (_Float16)y.z; r[7] = (_Float16)y.w;
    return r;
}
__device__ __forceinline__ float tanh_fast(float x){
    float e = __expf(2.f * x);
    return 1.f - 2.f / (e + 1.f);
}

// ci-block swizzle for conv LDS tiles (round-4 verified layout)
#define SWZ(c) ((((c) >> 1) & 3) << 3)

// ---------------------------------------------------------------------------
// K1 (MFMA): agg = tanh([nf|ef]@[Wn|We].T + bn + be); per-block row-sums ->
// part[cx][dblk][row]. BM=128, BN=64, BK=64, 512 thr, register prefetch.
// (round-8 version, verbatim)
// ---------------------------------------------------------------------------
__global__ __launch_bounds__(512) void gnn_kernel(
    const float* __restrict__ lig_nf, const float* __restrict__ lig_ef,
    const float* __restrict__ rec_nf, const float* __restrict__ rec_ef,
    const float* __restrict__ Wn, const float* __restrict__ We,
    const float* __restrict__ bn, const float* __restrict__ be,
    float* __restrict__ part)   // [2][16][1024]
{
    __shared__ __attribute__((aligned(16))) short As[128 * 64];
    __shared__ __attribute__((aligned(16))) short Bs[64 * 64];
    __shared__ float red[128][2];

    const int t  = threadIdx.x;
    const int cx = blockIdx.z;
    const float* A0 = cx ? rec_nf : lig_nf;
    const float* A1 = cx ? rec_ef : lig_ef;
    const int j0 = blockIdx.x * 128;
    const int d0 = blockIdx.y * 64;

    const int wid  = t >> 6;
    const int wm   = wid >> 1;
    const int wn   = wid & 1;
    const int lane = t & 63;
    const int lr   = lane & 15;
    const int lg   = lane >> 4;

    f32x4 acc[2][2];
    #pragma unroll
    for (int m = 0; m < 2; ++m)
        #pragma unroll
        for (int n = 0; n < 2; ++n)
            acc[m][n] = (f32x4){0.f, 0.f, 0.f, 0.f};

    const int arow = t >> 2;
    const int akc  = (t & 3) * 16;
    const int brow = t >> 3;
    const int bkc  = (t & 7) * 8;

    float4 av[4], bv[2];
    {
        const float* ap = A0 + (size_t)(j0 + arow) * 1024 + akc;
        const float* bp = Wn + (size_t)(d0 + brow) * 1024 + bkc;
        #pragma unroll
        for (int q = 0; q < 4; ++q) av[q] = *reinterpret_cast<const float4*>(ap + q * 4);
        #pragma unroll
        for (int q = 0; q < 2; ++q) bv[q] = *reinterpret_cast<const float4*>(bp + q * 4);
    }

    for (int kb = 0; kb < 2048; kb += 64){
        __syncthreads();
        {
            const int ga = (t & 3) * 2;
            const int sa = arow & 7;
            *reinterpret_cast<half8*>(&As[arow * 64 + ((ga    ) ^ sa) * 8]) = pack2(av[0], av[1]);
            *reinterpret_cast<half8*>(&As[arow * 64 + ((ga + 1) ^ sa) * 8]) = pack2(av[2], av[3]);
            *reinterpret_cast<half8*>(&Bs[brow * 64 + (((t & 7)) ^ (brow & 7)) * 8]) = pack2(bv[0], bv[1]);
        }
        {
            const int kbn = (kb + 64) & 2047;
            const float* Asrc = (kbn < 1024) ? A0 : A1;
            const float* Bsrc = (kbn < 1024) ? Wn : We;
            const int kk = kbn & 1023;
            const float* ap = Asrc + (size_t)(j0 + arow) * 1024 + kk + akc;
            const float* bp = Bsrc + (size_t)(d0 + brow) * 1024 + kk + bkc;
            #pragma unroll
            for (int q = 0; q < 4; ++q) av[q] = *reinterpret_cast<const float4*>(ap + q * 4);
            #pragma unroll
            for (int q = 0; q < 2; ++q) bv[q] = *reinterpret_cast<const float4*>(bp + q * 4);
        }
        __syncthreads();

        #pragma unroll
        for (int ks = 0; ks < 2; ++ks){
            half8 Af[2], Bf[2];
            #pragma unroll
            for (int m = 0; m < 2; ++m){
                int row = wm * 32 + m * 16 + lr;
                int g   = ((ks * 4 + lg) ^ (row & 7)) * 8;
                Af[m] = *reinterpret_cast<const half8*>(&As[row * 64 + g]);
            }
            #pragma unroll
            for (int n = 0; n < 2; ++n){
                int col = wn * 32 + n * 16 + lr;
                int g   = ((ks * 4 + lg) ^ (col & 7)) * 8;
                Bf[n] = *reinterpret_cast<const half8*>(&Bs[col * 64 + g]);
            }
            #pragma unroll
            for (int m = 0; m < 2; ++m)
                #pragma unroll
                for (int n = 0; n < 2; ++n)
                    acc[m][n] = __builtin_amdgcn_mfma_f32_16x16x32_f16(
                        Af[m], Bf[n], acc[m][n], 0, 0, 0);
        }
    }

    float rowsum[2][4];
    #pragma unroll
    for (int m = 0; m < 2; ++m)
        #pragma unroll
        for (int jj = 0; jj < 4; ++jj) rowsum[m][jj] = 0.f;
    #pragma unroll
    for (int n = 0; n < 2; ++n){
        int d = d0 + wn * 32 + n * 16 + lr;
        float bias = bn[d] + be[d];
        #pragma unroll
        for (int m = 0; m < 2; ++m)
            #pragma unroll
            for (int jj = 0; jj < 4; ++jj)
                rowsum[m][jj] += tanh_fast(acc[m][n][jj] + bias);
    }
    #pragma unroll
    for (int mask = 1; mask < 16; mask <<= 1)
        #pragma unroll
        for (int m = 0; m < 2; ++m)
            #pragma unroll
            for (int jj = 0; jj < 4; ++jj)
                rowsum[m][jj] += __shfl_xor(rowsum[m][jj], mask);
    __syncthreads();
    if (lr == 0){
        #pragma unroll
        for (int m = 0; m < 2; ++m)
            #pragma unroll
            for (int jj = 0; jj < 4; ++jj)
                red[wm * 32 + m * 16 + lg * 4 + jj][wn] = rowsum[m][jj];
    }
    __syncthreads();
    if (t < 128)
        part[(size_t)cx * 16384 + (size_t)blockIdx.y * 1024 + j0 + t]
            = red[t][0] + red[t][1];
}

// ---------------------------------------------------------------------------
// K2a: PL[i,h] = sum_j nf[i,j]*Wl[h,j]; PR analog. grid (128,2), block 256
// ---------------------------------------------------------------------------
__global__ __launch_bounds__(256) void proj_kernel(
    const float* __restrict__ lig_nf, const float* __restrict__ rec_nf,
    const float* __restrict__ W_hopi, float* __restrict__ PL, float* __restrict__ PR)
{
    const int t  = threadIdx.x;
    const int cx = blockIdx.y;
    const float* nf = cx ? rec_nf : lig_nf;
    const float* W  = W_hopi + (cx ? 1024 : 0);
    float* outp     = cx ? PR : PL;
    const int h = t & 31;
    const int i = blockIdx.x * 8 + (t >> 5);
    const float* nrow = nf + (size_t)i * 1024;
    const float* wrow = W + (size_t)h * 2048;
    float s0 = 0.f, s1 = 0.f;
    #pragma unroll 4
    for (int j = 0; j < 1024; j += 8){
        float4 a0 = *reinterpret_cast<const float4*>(nrow + j);
        float4 b0 = *reinterpret_cast<const float4*>(wrow + j);
        float4 a1 = *reinterpret_cast<const float4*>(nrow + j + 4);
        float4 b1 = *reinterpret_cast<const float4*>(wrow + j + 4);
        s0 = fmaf(a0.x, b0.x, s0); s0 = fmaf(a0.y, b0.y, s0);
        s0 = fmaf(a0.z, b0.z, s0); s0 = fmaf(a0.w, b0.w, s0);
        s1 = fmaf(a1.x, b1.x, s1); s1 = fmaf(a1.y, b1.y, s1);
        s1 = fmaf(a1.z, b1.z, s1); s1 = fmaf(a1.w, b1.w, s1);
    }
    outp[(size_t)i * 32 + h] = s0 + s1;
}

// ---------------------------------------------------------------------------
// K2b: w[j] = block-sum of part; c[h] = b_hopi[h] + wL.Wl[h] + wR.Wr[h];
// then K'[yc][xc][co] = b1[co] + sum_ci c[ci] * sum_{dy in D(yc), dx in D(xc)} w1
// D(0)={0,1,2} (interior), D(1)={1,2} (coord==0), D(2)={0,1} (coord==1023)
// ---------------------------------------------------------------------------
__global__ __launch_bounds__(256) void cveck_kernel(
    const float* __restrict__ W_hopi, const float* __restrict__ b_hopi,
    const float* __restrict__ w1, const float* __restrict__ b1,
    const float* __restrict__ part, float* __restrict__ Kp)   // [3][3][32]
{
    __shared__ float ws_l[1024];
    __shared__ float ws_r[1024];
    __shared__ float red[256];
    __shared__ float cvs[32];
    const int t = threadIdx.x;
    for (int j = t; j < 1024; j += 256){
        float sl = 0.f, sr = 0.f;
        #pragma unroll
        for (int b = 0; b < 16; ++b){
            sl += part[b * 1024 + j];
            sr += part[16384 + b * 1024 + j];
        }
        ws_l[j] = sl; ws_r[j] = sr;
    }
    __syncthreads();
    const int h = t & 31;
    const int seg = t >> 5;
    float s = 0.f;
    for (int j = seg * 128; j < seg * 128 + 128; ++j){
        s = fmaf(ws_l[j], W_hopi[(size_t)h * 2048 + j], s);
        s = fmaf(ws_r[j], W_hopi[(size_t)h * 2048 + 1024 + j], s);
    }
    red[t] = s;
    __syncthreads();
    if (t < 32){
        float tot = b_hopi[t];
        #pragma unroll
        for (int g = 0; g < 8; ++g) tot += red[g * 32 + t];
        cvs[t] = tot;
    }
    __syncthreads();
    for (int e = t; e < 288; e += 256){
        int co  = e & 31;
        int cse = e >> 5;                 // 0..8 = yc*3+xc
        int yc  = cse / 3, xc = cse - yc * 3;
        int ylo = (yc == 1) ? 1 : 0, yhi = (yc == 2) ? 1 : 2;
        int xlo = (xc == 1) ? 1 : 0, xhi = (xc == 2) ? 1 : 2;
        float sum = b1[co];
        for (int ci = 0; ci < 32; ++ci){
            float wsum = 0.f;
            for (int dy = ylo; dy <= yhi; ++dy)
                for (int dx = xlo; dx <= xhi; ++dx)
                    wsum += w1[co * 288 + ci * 9 + dy * 3 + dx];
            sum = fmaf(cvs[ci], wsum, sum);
        }
        Kp[cse * 32 + co] = sum;
    }
}

// ---------------------------------------------------------------------------
// K2c: U[xc][y][co] = sum_{dy,ci} PLpad[y-1+dy,ci] * (sum_{dx in D(xc)} w1)
//      V[yc][x][co] = sum_{dx,ci} PRpad[x-1+dx,ci] * (sum_{dy in D(yc)} w1)
// stored f16. grid (16, 3, 2): 64 y per block, case, {U,V}. block 256.
// ---------------------------------------------------------------------------
__global__ __launch_bounds__(256) void uv_kernel(
    const float* __restrict__ PL, const float* __restrict__ PR,
    const float* __restrict__ w1,
    short* __restrict__ U16, short* __restrict__ V16)
{
    __shared__ float Ws[3 * 32 * 32];   // [d][ci][co], d = dy for U, dx for V
    const int t  = threadIdx.x;
    const int yb = blockIdx.x;          // 0..15
    const int cs = blockIdx.y;          // 0..2
    const int uv = blockIdx.z;          // 0:U(PL), 1:V(PR)
    const float* P = uv ? PR : PL;
    short* O = uv ? V16 : U16;
    const int o_lo = (cs == 1) ? 1 : 0;
    const int o_hi = (cs == 2) ? 1 : 2;

    for (int e = t; e < 3072; e += 256){
        int co = e & 31;
        int q  = e >> 5;                // 0..95: d = q>>5, ci = q&31
        int d  = q >> 5;
        int ci = q & 31;
        float s = 0.f;
        for (int o = o_lo; o <= o_hi; ++o){
            int tap = uv ? (o * 3 + d) : (d * 3 + o);
            s += w1[co * 288 + ci * 9 + tap];
        }
        Ws[q * 32 + co] = s;
    }
    __syncthreads();

    const int co = t & 31;
    const int yi = t >> 5;              // 0..7
    #pragma unroll
    for (int r = 0; r < 8; ++r){
        int y = yb * 64 + r * 8 + yi;
        float acc = 0.f;
        #pragma unroll
        for (int d = 0; d < 3; ++d){
            int row = y - 1 + d;
            if (row >= 0 && row < 1024){
                const float* pr = P + (size_t)row * 32;
                const float* ws = Ws + d * 1024 + co;
                #pragma unroll
                for (int ci = 0; ci < 32; ++ci)
                    acc = fmaf(pr[ci], ws[ci * 32], acc);
            }
        }
        O[((size_t)cs * 1024 + y) * 32 + co] = f2h_bits(acc);
    }
}

// ---------------------------------------------------------------------------
// K3: stage ys = relu(U+V+K') directly, then conv2+relu+conv3 on f16 MFMA
// (conv2/conv3 = round-4 verbatim). LDS = 39,168 B. block 512, grid 64x64.
// ---------------------------------------------------------------------------
__global__ __launch_bounds__(512) void conv_kernel(
    const short* __restrict__ U16, const short* __restrict__ V16,
    const float* __restrict__ Kp,
    const float* __restrict__ w2, const float* __restrict__ b2,
    const float* __restrict__ w3, const float* __restrict__ b3,
    float* __restrict__ outp)
{
    __shared__ __attribute__((aligned(16))) short ys[18 * 18 * 32];
    __shared__ __attribute__((aligned(16))) short wB[9 * 32 * 32];

    const int t    = threadIdx.x;
    const int oy0  = blockIdx.y * 16;
    const int ox0  = blockIdx.x * 16;
    const int wid  = t >> 6;
    const int lane = t & 63;
    const int lr   = lane & 15;
    const int lg   = lane >> 4;

    // ---- stage ys: 324 px x 32 k (= conv1 co), y1 = relu(U+V+K') ----
    #pragma unroll
    for (int pass = 0; pass < 6; ++pass){
        int idx = t + pass * 512;
        if (idx < 2592){
            int po  = idx >> 3;
            int cp  = (idx & 7) * 4;
            int ryo = po / 18;
            int rxo = po - ryo * 18;
            int gy = oy0 - 1 + ryo, gx = ox0 - 1 + rxo;
            half4 h = {(_Float16)0.f, (_Float16)0.f, (_Float16)0.f, (_Float16)0.f};
            if ((unsigned)gy < 1024u && (unsigned)gx < 1024u){
                int yc = (gy == 0) ? 1 : ((gy == 1023) ? 2 : 0);
                int xc = (gx == 0) ? 1 : ((gx == 1023) ? 2 : 0);
                half4 u = *reinterpret_cast<const half4*>(
                    &U16[((size_t)(xc << 10) + gy) * 32 + cp]);
                half4 v = *reinterpret_cast<const half4*>(
                    &V16[((size_t)(yc << 10) + gx) * 32 + cp]);
                float4 k = *reinterpret_cast<const float4*>(&Kp[(yc * 3 + xc) * 32 + cp]);
                h[0] = (_Float16)fmaxf((float)u[0] + (float)v[0] + k.x, 0.f);
                h[1] = (_Float16)fmaxf((float)u[1] + (float)v[1] + k.y, 0.f);
                h[2] = (_Float16)fmaxf((float)u[2] + (float)v[2] + k.z, 0.f);
                h[3] = (_Float16)fmaxf((float)u[3] + (float)v[3] + k.w, 0.f);
            }
            *reinterpret_cast<half4*>(&ys[po * 32 + (cp ^ SWZ(rxo))]) = h;
        }
    }
    // ---- stage conv2 weights ----
    for (int e = t; e < 9216; e += 512){
        int co  = e / 288;
        int rem = e - co * 288;
        int ci  = rem / 9;
        int tap = rem - ci * 9;
        wB[(tap * 32 + co) * 32 + (ci ^ SWZ(co))] = f2h_bits(w2[e]);
    }
    __syncthreads();

    // ================= conv2 + conv3: 256 outputs (round-4 verbatim) ======
    {
        half8 Bf[2][9];
        float bias[2], w3v[2];
        #pragma unroll
        for (int n = 0; n < 2; ++n){
            int co = n * 16 + lr;
            bias[n] = b2[co];
            w3v[n]  = w3[co];
            #pragma unroll
            for (int tap = 0; tap < 9; ++tap)
                Bf[n][tap] = *reinterpret_cast<const half8*>(
                    &wB[(tap * 32 + co) * 32 + ((lg * 8) ^ SWZ(co))]);
        }
        const float b3v = b3[0];
        for (int s = wid; s < 16; s += 8){
            int p  = s * 16 + lr;
            int ry = p >> 4;
            int rx = p & 15;
            f32x4 acc0 = {0.f, 0.f, 0.f, 0.f};
            f32x4 acc1 = {0.f, 0.f, 0.f, 0.f};
            #pragma unroll
            for (int tap = 0; tap < 9; ++tap){
                const int dy = tap / 3, dx = tap - (tap / 3) * 3;
                int pix = (ry + dy) * 18 + rx + dx;
                half8 A = *reinterpret_cast<const half8*>(
                    &ys[pix * 32 + ((lg * 8) ^ SWZ(rx + dx))]);
                acc0 = __builtin_amdgcn_mfma_f32_16x16x32_f16(A, Bf[0][tap], acc0, 0, 0, 0);
                acc1 = __builtin_amdgcn_mfma_f32_16x16x32_f16(A, Bf[1][tap], acc1, 0, 0, 0);
            }
            float part[4];
            #pragma unroll
            for (int j = 0; j < 4; ++j)
                part[j] = w3v[0] * fmaxf(acc0[j] + bias[0], 0.f)
                        + w3v[1] * fmaxf(acc1[j] + bias[1], 0.f);
            #pragma unroll
            for (int m = 1; m < 16; m <<= 1)
                #pragma unroll
                for (int j = 0; j < 4; ++j)
                    part[j] += __shfl_xor(part[j], m);
            if (lr == 0){
                float4 o = make_float4(part[0] + b3v, part[1] + b3v,
                                       part[2] + b3v, part[3] + b3v);
                *reinterpret_cast<float4*>(outp + (size_t)(oy0 + s) * 1024 + ox0 + lg * 4) = o;
            }
        }
    }
}

// ---------------------------------------------------------------------------
extern "C" void kernel_launch(void* const* d_in, const int* in_sizes, int n_in,
                              void* d_out, int out_size, void* d_ws, size_t ws_size,
                              hipStream_t stream)
{
    const float* lig_nf = (const float*)d_in[0];
    const float* lig_ef = (const float*)d_in[1];
    const float* rec_nf = (const float*)d_in[3];
    const float* rec_ef = (const float*)d_in[4];
    const float* Wn     = (const float*)d_in[6];
    const float* bn     = (const float*)d_in[7];
    const float* We     = (const float*)d_in[8];
    const float* be     = (const float*)d_in[9];
    const float* W_hopi = (const float*)d_in[12];
    const float* b_hopi = (const float*)d_in[13];
    const float* w1     = (const float*)d_in[14];
    const float* b1     = (const float*)d_in[15];
    const float* w2     = (const float*)d_in[16];
    const float* b2     = (const float*)d_in[17];
    const float* w3     = (const float*)d_in[18];
    const float* b3     = (const float*)d_in[19];
    float* outp = (float*)d_out;

    float* part = (float*)d_ws;                               // [2][16][1024] f32
    float* PL   = (float*)((char*)d_ws + 131072);             // 1024*32 f32
    float* PR   = (float*)((char*)d_ws + 262144);             // 1024*32 f32
    float* Kp   = (float*)((char*)d_ws + 393216);             // 3*3*32 f32
    short* U16  = (short*)((char*)d_ws + 394368);             // 3*1024*32 f16
    short* V16  = (short*)((char*)d_ws + 590976);             // 3*1024*32 f16
                                                              // ends at 787584

    dim3 g1(8, 16, 2);
    gnn_kernel<<<g1, 512, 0, stream>>>(lig_nf, lig_ef, rec_nf, rec_ef,
                                       Wn, We, bn, be, part);
    dim3 g2(128, 2);
    proj_kernel<<<g2, 256, 0, stream>>>(lig_nf, rec_nf, W_hopi, PL, PR);
    cveck_kernel<<<1, 256, 0, stream>>>(W_hopi, b_hopi, w1, b1, part, Kp);
    dim3 g4(16, 3, 2);
    uv_kernel<<<g4, 256, 0, stream>>>(PL, PR, w1, U16, V16);
    dim3 g3(64, 64);
    conv_kernel<<<g3, 512, 0, stream>>>(U16, V16, Kp, w2, b2, w3, b3, outp);
}

// Round 10
// 190.502 us; speedup vs baseline: 2.1898x; 1.1679x over previous
//
#include <hip/hip_runtime.h>

// All tensors float32. Math structure exploited:
//  - softmax over axis of size 1 == 1.0 -> attn all-ones, Wa/ba dead.
//  - weighted = row-sum of tanh(agg), broadcast over COLUMNS (N==D quirk).
//  - lig_p = nf@Wl.T + const  ->  x0[h,i,j] = PL[i,h] + PR[j,h] + c[h]
//  - conv1 is LINEAR in rank-structured x0: y1_pre = U[xc][y] + V[yc][x] + K',
//    U/V = 1D convs of PL/PR, border cases factorized 3x3. conv kernel stages
//    ys = relu(U+V+K') directly; conv2+conv3 = round-4 verbatim.
//  - gnn GEMM on f16 MFMA with register prefetch (round-8 version).
//  - ROUND-10: cveck was 78.7 us -- single block issuing ~192 serial global
//    loads of w1 with runtime loop bounds (no unroll, ~900 cyc each). Fix:
//    stage w1 in LDS (pipelined float4), unrolled 9-tap row-sum selection.

typedef _Float16 half8 __attribute__((ext_vector_type(8)));
typedef _Float16 half4 __attribute__((ext_vector_type(4)));
typedef float    f32x4 __attribute__((ext_vector_type(4)));

__device__ __forceinline__ short f2h_bits(float f){
    _Float16 h = (_Float16)f;          // RNE
    return __builtin_bit_cast(short, h);
}
__device__ __forceinline__ half8 pack2(const float4& x, const float4& y){
    half8 r;
    r[0] = (_Float16)x.x; r[1] = (_Float16)x.y;
    r[2] = (_Float16)x.z; r[3] = (_Float16)x.w;
    r[4] = (_Float16)y.x; r[5] = (_Float16)y.y;
    r[6] = (_Float16)y.z; r[7] = (_Float16)y.w;
    return r;
}
__device__ __forceinline__ float tanh_fast(float x){
    float e = __expf(2.f * x);
    return 1.f - 2.f / (e + 1.f);
}

// ci-block swizzle for conv LDS tiles (round-4 verified layout)
#define SWZ(c) ((((c) >> 1) & 3) << 3)

// ---------------------------------------------------------------------------
// K1 (MFMA): agg = tanh([nf|ef]@[Wn|We].T + bn + be); per-block row-sums ->
// part[cx][dblk][row]. BM=128, BN=64, BK=64, 512 thr, register prefetch.
// ---------------------------------------------------------------------------
__global__ __launch_bounds__(512) void gnn_kernel(
    const float* __restrict__ lig_nf, const float* __restrict__ lig_ef,
    const float* __restrict__ rec_nf, const float* __restrict__ rec_ef,
    const float* __restrict__ Wn, const float* __restrict__ We,
    const float* __restrict__ bn, const float* __restrict__ be,
    float* __restrict__ part)   // [2][16][1024]
{
    __shared__ __attribute__((aligned(16))) short As[128 * 64];
    __shared__ __attribute__((aligned(16))) short Bs[64 * 64];
    __shared__ float red[128][2];

    const int t  = threadIdx.x;
    const int cx = blockIdx.z;
    const float* A0 = cx ? rec_nf : lig_nf;
    const float* A1 = cx ? rec_ef : lig_ef;
    const int j0 = blockIdx.x * 128;
    const int d0 = blockIdx.y * 64;

    const int wid  = t >> 6;
    const int wm   = wid >> 1;
    const int wn   = wid & 1;
    const int lane = t & 63;
    const int lr   = lane & 15;
    const int lg   = lane >> 4;

    f32x4 acc[2][2];
    #pragma unroll
    for (int m = 0; m < 2; ++m)
        #pragma unroll
        for (int n = 0; n < 2; ++n)
            acc[m][n] = (f32x4){0.f, 0.f, 0.f, 0.f};

    const int arow = t >> 2;
    const int akc  = (t & 3) * 16;
    const int brow = t >> 3;
    const int bkc  = (t & 7) * 8;

    float4 av[4], bv[2];
    {
        const float* ap = A0 + (size_t)(j0 + arow) * 1024 + akc;
        const float* bp = Wn + (size_t)(d0 + brow) * 1024 + bkc;
        #pragma unroll
        for (int q = 0; q < 4; ++q) av[q] = *reinterpret_cast<const float4*>(ap + q * 4);
        #pragma unroll
        for (int q = 0; q < 2; ++q) bv[q] = *reinterpret_cast<const float4*>(bp + q * 4);
    }

    for (int kb = 0; kb < 2048; kb += 64){
        __syncthreads();
        {
            const int ga = (t & 3) * 2;
            const int sa = arow & 7;
            *reinterpret_cast<half8*>(&As[arow * 64 + ((ga    ) ^ sa) * 8]) = pack2(av[0], av[1]);
            *reinterpret_cast<half8*>(&As[arow * 64 + ((ga + 1) ^ sa) * 8]) = pack2(av[2], av[3]);
            *reinterpret_cast<half8*>(&Bs[brow * 64 + (((t & 7)) ^ (brow & 7)) * 8]) = pack2(bv[0], bv[1]);
        }
        {
            const int kbn = (kb + 64) & 2047;
            const float* Asrc = (kbn < 1024) ? A0 : A1;
            const float* Bsrc = (kbn < 1024) ? Wn : We;
            const int kk = kbn & 1023;
            const float* ap = Asrc + (size_t)(j0 + arow) * 1024 + kk + akc;
            const float* bp = Bsrc + (size_t)(d0 + brow) * 1024 + kk + bkc;
            #pragma unroll
            for (int q = 0; q < 4; ++q) av[q] = *reinterpret_cast<const float4*>(ap + q * 4);
            #pragma unroll
            for (int q = 0; q < 2; ++q) bv[q] = *reinterpret_cast<const float4*>(bp + q * 4);
        }
        __syncthreads();

        #pragma unroll
        for (int ks = 0; ks < 2; ++ks){
            half8 Af[2], Bf[2];
            #pragma unroll
            for (int m = 0; m < 2; ++m){
                int row = wm * 32 + m * 16 + lr;
                int g   = ((ks * 4 + lg) ^ (row & 7)) * 8;
                Af[m] = *reinterpret_cast<const half8*>(&As[row * 64 + g]);
            }
            #pragma unroll
            for (int n = 0; n < 2; ++n){
                int col = wn * 32 + n * 16 + lr;
                int g   = ((ks * 4 + lg) ^ (col & 7)) * 8;
                Bf[n] = *reinterpret_cast<const half8*>(&Bs[col * 64 + g]);
            }
            #pragma unroll
            for (int m = 0; m < 2; ++m)
                #pragma unroll
                for (int n = 0; n < 2; ++n)
                    acc[m][n] = __builtin_amdgcn_mfma_f32_16x16x32_f16(
                        Af[m], Bf[n], acc[m][n], 0, 0, 0);
        }
    }

    float rowsum[2][4];
    #pragma unroll
    for (int m = 0; m < 2; ++m)
        #pragma unroll
        for (int jj = 0; jj < 4; ++jj) rowsum[m][jj] = 0.f;
    #pragma unroll
    for (int n = 0; n < 2; ++n){
        int d = d0 + wn * 32 + n * 16 + lr;
        float bias = bn[d] + be[d];
        #pragma unroll
        for (int m = 0; m < 2; ++m)
            #pragma unroll
            for (int jj = 0; jj < 4; ++jj)
                rowsum[m][jj] += tanh_fast(acc[m][n][jj] + bias);
    }
    #pragma unroll
    for (int mask = 1; mask < 16; mask <<= 1)
        #pragma unroll
        for (int m = 0; m < 2; ++m)
            #pragma unroll
            for (int jj = 0; jj < 4; ++jj)
                rowsum[m][jj] += __shfl_xor(rowsum[m][jj], mask);
    __syncthreads();
    if (lr == 0){
        #pragma unroll
        for (int m = 0; m < 2; ++m)
            #pragma unroll
            for (int jj = 0; jj < 4; ++jj)
                red[wm * 32 + m * 16 + lg * 4 + jj][wn] = rowsum[m][jj];
    }
    __syncthreads();
    if (t < 128)
        part[(size_t)cx * 16384 + (size_t)blockIdx.y * 1024 + j0 + t]
            = red[t][0] + red[t][1];
}

// ---------------------------------------------------------------------------
// K2a: PL[i,h] = sum_j nf[i,j]*Wl[h,j]; PR analog. grid (128,2), block 256
// ---------------------------------------------------------------------------
__global__ __launch_bounds__(256) void proj_kernel(
    const float* __restrict__ lig_nf, const float* __restrict__ rec_nf,
    const float* __restrict__ W_hopi, float* __restrict__ PL, float* __restrict__ PR)
{
    const int t  = threadIdx.x;
    const int cx = blockIdx.y;
    const float* nf = cx ? rec_nf : lig_nf;
    const float* W  = W_hopi + (cx ? 1024 : 0);
    float* outp     = cx ? PR : PL;
    const int h = t & 31;
    const int i = blockIdx.x * 8 + (t >> 5);
    const float* nrow = nf + (size_t)i * 1024;
    const float* wrow = W + (size_t)h * 2048;
    float s0 = 0.f, s1 = 0.f;
    #pragma unroll 4
    for (int j = 0; j < 1024; j += 8){
        float4 a0 = *reinterpret_cast<const float4*>(nrow + j);
        float4 b0 = *reinterpret_cast<const float4*>(wrow + j);
        float4 a1 = *reinterpret_cast<const float4*>(nrow + j + 4);
        float4 b1 = *reinterpret_cast<const float4*>(wrow + j + 4);
        s0 = fmaf(a0.x, b0.x, s0); s0 = fmaf(a0.y, b0.y, s0);
        s0 = fmaf(a0.z, b0.z, s0); s0 = fmaf(a0.w, b0.w, s0);
        s1 = fmaf(a1.x, b1.x, s1); s1 = fmaf(a1.y, b1.y, s1);
        s1 = fmaf(a1.z, b1.z, s1); s1 = fmaf(a1.w, b1.w, s1);
    }
    outp[(size_t)i * 32 + h] = s0 + s1;
}

// ---------------------------------------------------------------------------
// K2b: w[j] = block-sum of part; c[h] = b_hopi[h] + wL.Wl[h] + wR.Wr[h];
// K'[yc][xc][co] = b1[co] + sum_ci c[ci] * S(yc,xc,co,ci)
// S = sum over taps with dy in D(yc), dx in D(xc); D(0)={0,1,2}, D(1)={1,2},
// D(2)={0,1}. w1 staged in LDS; taps fully unrolled (round-10 fix).
// ---------------------------------------------------------------------------
__global__ __launch_bounds__(256) void cveck_kernel(
    const float* __restrict__ W_hopi, const float* __restrict__ b_hopi,
    const float* __restrict__ w1, const float* __restrict__ b1,
    const float* __restrict__ part, float* __restrict__ Kp)   // [3][3][32]
{
    __shared__ float ws_l[1024];
    __shared__ float ws_r[1024];
    __shared__ float red[256];
    __shared__ float cvs[32];
    __shared__ float w1s[9216];    // 36 KB, [co*288 + ci*9 + tap]

    const int t = threadIdx.x;
    // stage w1 -> LDS (float4 x 9 per thread, pipelined)
    #pragma unroll
    for (int q = 0; q < 9; ++q){
        int idx = (t + q * 256) * 4;
        *reinterpret_cast<float4*>(&w1s[idx]) =
            *reinterpret_cast<const float4*>(w1 + idx);
    }
    // part reduction (independent loads, pipelined)
    for (int j = t; j < 1024; j += 256){
        float sl = 0.f, sr = 0.f;
        #pragma unroll
        for (int b = 0; b < 16; ++b){
            sl += part[b * 1024 + j];
            sr += part[16384 + b * 1024 + j];
        }
        ws_l[j] = sl; ws_r[j] = sr;
    }
    __syncthreads();
    // c[h] = b_hopi[h] + wL.Wl[h] + wR.Wr[h]  (float4 global reads)
    {
        const int h = t & 31;
        const int seg = t >> 5;
        const float* wl = W_hopi + (size_t)h * 2048 + seg * 128;
        const float* wr = wl + 1024;
        float s = 0.f;
        #pragma unroll 8
        for (int j = 0; j < 128; j += 4){
            float4 a = *reinterpret_cast<const float4*>(wl + j);
            float4 b = *reinterpret_cast<const float4*>(wr + j);
            const float* l = &ws_l[seg * 128 + j];
            const float* r = &ws_r[seg * 128 + j];
            s = fmaf(l[0], a.x, s); s = fmaf(l[1], a.y, s);
            s = fmaf(l[2], a.z, s); s = fmaf(l[3], a.w, s);
            s = fmaf(r[0], b.x, s); s = fmaf(r[1], b.y, s);
            s = fmaf(r[2], b.z, s); s = fmaf(r[3], b.w, s);
        }
        red[t] = s;
    }
    __syncthreads();
    if (t < 32){
        float tot = b_hopi[t];
        #pragma unroll
        for (int g = 0; g < 8; ++g) tot += red[g * 32 + t];
        cvs[t] = tot;
    }
    __syncthreads();
    // K' : unrolled taps from LDS, case-select via uniform yc/xc
    for (int e = t; e < 288; e += 256){
        int co  = e & 31;
        int cse = e >> 5;                 // 0..8 = yc*3+xc
        int yc  = cse / 3, xc = cse - yc * 3;
        float sum = b1[co];
        for (int ci = 0; ci < 32; ++ci){
            const float* wp = &w1s[co * 288 + ci * 9];
            float t00 = wp[0], t01 = wp[1], t02 = wp[2];
            float t10 = wp[3], t11 = wp[4], t12 = wp[5];
            float t20 = wp[6], t21 = wp[7], t22 = wp[8];
            float r0, r1, r2;
            if (xc == 0){ r0 = t00+t01+t02; r1 = t10+t11+t12; r2 = t20+t21+t22; }
            else if (xc == 1){ r0 = t01+t02; r1 = t11+t12; r2 = t21+t22; }
            else { r0 = t00+t01; r1 = t10+t11; r2 = t20+t21; }
            float wsum = (yc == 0) ? (r0+r1+r2) : ((yc == 1) ? (r1+r2) : (r0+r1));
            sum = fmaf(cvs[ci], wsum, sum);
        }
        Kp[cse * 32 + co] = sum;
    }
}

// ---------------------------------------------------------------------------
// K2c: U[xc][y][co], V[yc][x][co] 1D convs of PL/PR. grid (16,3,2), block 256
// ---------------------------------------------------------------------------
__global__ __launch_bounds__(256) void uv_kernel(
    const float* __restrict__ PL, const float* __restrict__ PR,
    const float* __restrict__ w1,
    short* __restrict__ U16, short* __restrict__ V16)
{
    __shared__ float Ws[3 * 32 * 32];   // [d][ci][co], d = dy for U, dx for V
    const int t  = threadIdx.x;
    const int yb = blockIdx.x;          // 0..15
    const int cs = blockIdx.y;          // 0..2
    const int uv = blockIdx.z;          // 0:U(PL), 1:V(PR)
    const float* P = uv ? PR : PL;
    short* O = uv ? V16 : U16;
    const int o_lo = (cs == 1) ? 1 : 0;
    const int o_hi = (cs == 2) ? 1 : 2;

    for (int e = t; e < 3072; e += 256){
        int co = e & 31;
        int q  = e >> 5;                // 0..95: d = q>>5, ci = q&31
        int d  = q >> 5;
        int ci = q & 31;
        float s = 0.f;
        for (int o = o_lo; o <= o_hi; ++o){
            int tap = uv ? (o * 3 + d) : (d * 3 + o);
            s += w1[co * 288 + ci * 9 + tap];
        }
        Ws[q * 32 + co] = s;
    }
    __syncthreads();

    const int co = t & 31;
    const int yi = t >> 5;              // 0..7
    #pragma unroll
    for (int r = 0; r < 8; ++r){
        int y = yb * 64 + r * 8 + yi;
        float acc = 0.f;
        #pragma unroll
        for (int d = 0; d < 3; ++d){
            int row = y - 1 + d;
            if (row >= 0 && row < 1024){
                const float* pr = P + (size_t)row * 32;
                const float* ws = Ws + d * 1024 + co;
                #pragma unroll
                for (int ci = 0; ci < 32; ++ci)
                    acc = fmaf(pr[ci], ws[ci * 32], acc);
            }
        }
        O[((size_t)cs * 1024 + y) * 32 + co] = f2h_bits(acc);
    }
}

// ---------------------------------------------------------------------------
// K3: stage ys = relu(U+V+K'), then conv2+relu+conv3 on f16 MFMA.
// LDS = 39,168 B. block 512, grid 64x64.
// ---------------------------------------------------------------------------
__global__ __launch_bounds__(512) void conv_kernel(
    const short* __restrict__ U16, const short* __restrict__ V16,
    const float* __restrict__ Kp,
    const float* __restrict__ w2, const float* __restrict__ b2,
    const float* __restrict__ w3, const float* __restrict__ b3,
    float* __restrict__ outp)
{
    __shared__ __attribute__((aligned(16))) short ys[18 * 18 * 32];
    __shared__ __attribute__((aligned(16))) short wB[9 * 32 * 32];

    const int t    = threadIdx.x;
    const int oy0  = blockIdx.y * 16;
    const int ox0  = blockIdx.x * 16;
    const int wid  = t >> 6;
    const int lane = t & 63;
    const int lr   = lane & 15;
    const int lg   = lane >> 4;

    // ---- stage ys: 324 px x 32 k, y1 = relu(U+V+K') ----
    #pragma unroll
    for (int pass = 0; pass < 6; ++pass){
        int idx = t + pass * 512;
        if (idx < 2592){
            int po  = idx >> 3;
            int cp  = (idx & 7) * 4;
            int ryo = po / 18;
            int rxo = po - ryo * 18;
            int gy = oy0 - 1 + ryo, gx = ox0 - 1 + rxo;
            half4 h = {(_Float16)0.f, (_Float16)0.f, (_Float16)0.f, (_Float16)0.f};
            if ((unsigned)gy < 1024u && (unsigned)gx < 1024u){
                int yc = (gy == 0) ? 1 : ((gy == 1023) ? 2 : 0);
                int xc = (gx == 0) ? 1 : ((gx == 1023) ? 2 : 0);
                half4 u = *reinterpret_cast<const half4*>(
                    &U16[((size_t)(xc << 10) + gy) * 32 + cp]);
                half4 v = *reinterpret_cast<const half4*>(
                    &V16[((size_t)(yc << 10) + gx) * 32 + cp]);
                float4 k = *reinterpret_cast<const float4*>(&Kp[(yc * 3 + xc) * 32 + cp]);
                h[0] = (_Float16)fmaxf((float)u[0] + (float)v[0] + k.x, 0.f);
                h[1] = (_Float16)fmaxf((float)u[1] + (float)v[1] + k.y, 0.f);
                h[2] = (_Float16)fmaxf((float)u[2] + (float)v[2] + k.z, 0.f);
                h[3] = (_Float16)fmaxf((float)u[3] + (float)v[3] + k.w, 0.f);
            }
            *reinterpret_cast<half4*>(&ys[po * 32 + (cp ^ SWZ(rxo))]) = h;
        }
    }
    // ---- stage conv2 weights ----
    for (int e = t; e < 9216; e += 512){
        int co  = e / 288;
        int rem = e - co * 288;
        int ci  = rem / 9;
        int tap = rem - ci * 9;
        wB[(tap * 32 + co) * 32 + (ci ^ SWZ(co))] = f2h_bits(w2[e]);
    }
    __syncthreads();

    // ================= conv2 + conv3: 256 outputs (round-4 verbatim) ======
    {
        half8 Bf[2][9];
        float bias[2], w3v[2];
        #pragma unroll
        for (int n = 0; n < 2; ++n){
            int co = n * 16 + lr;
            bias[n] = b2[co];
            w3v[n]  = w3[co];
            #pragma unroll
            for (int tap = 0; tap < 9; ++tap)
                Bf[n][tap] = *reinterpret_cast<const half8*>(
                    &wB[(tap * 32 + co) * 32 + ((lg * 8) ^ SWZ(co))]);
        }
        const float b3v = b3[0];
        for (int s = wid; s < 16; s += 8){
            int p  = s * 16 + lr;
            int ry = p >> 4;
            int rx = p & 15;
            f32x4 acc0 = {0.f, 0.f, 0.f, 0.f};
            f32x4 acc1 = {0.f, 0.f, 0.f, 0.f};
            #pragma unroll
            for (int tap = 0; tap < 9; ++tap){
                const int dy = tap / 3, dx = tap - (tap / 3) * 3;
                int pix = (ry + dy) * 18 + rx + dx;
                half8 A = *reinterpret_cast<const half8*>(
                    &ys[pix * 32 + ((lg * 8) ^ SWZ(rx + dx))]);
                acc0 = __builtin_amdgcn_mfma_f32_16x16x32_f16(A, Bf[0][tap], acc0, 0, 0, 0);
                acc1 = __builtin_amdgcn_mfma_f32_16x16x32_f16(A, Bf[1][tap], acc1, 0, 0, 0);
            }
            float part[4];
            #pragma unroll
            for (int j = 0; j < 4; ++j)
                part[j] = w3v[0] * fmaxf(acc0[j] + bias[0], 0.f)
                        + w3v[1] * fmaxf(acc1[j] + bias[1], 0.f);
            #pragma unroll
            for (int m = 1; m < 16; m <<= 1)
                #pragma unroll
                for (int j = 0; j < 4; ++j)
                    part[j] += __shfl_xor(part[j], m);
            if (lr == 0){
                float4 o = make_float4(part[0] + b3v, part[1] + b3v,
                                       part[2] + b3v, part[3] + b3v);
                *reinterpret_cast<float4*>(outp + (size_t)(oy0 + s) * 1024 + ox0 + lg * 4) = o;
            }
        }
    }
}

// ---------------------------------------------------------------------------
extern "C" void kernel_launch(void* const* d_in, const int* in_sizes, int n_in,
                              void* d_out, int out_size, void* d_ws, size_t ws_size,
                              hipStream_t stream)
{
    const float* lig_nf = (const float*)d_in[0];
    const float* lig_ef = (const float*)d_in[1];
    const float* rec_nf = (const float*)d_in[3];
    const float* rec_ef = (const float*)d_in[4];
    const float* Wn     = (const float*)d_in[6];
    const float* bn     = (const float*)d_in[7];
    const float* We     = (const float*)d_in[8];
    const float* be     = (const float*)d_in[9];
    const float* W_hopi = (const float*)d_in[12];
    const float* b_hopi = (const float*)d_in[13];
    const float* w1     = (const float*)d_in[14];
    const float* b1     = (const float*)d_in[15];
    const float* w2     = (const float*)d_in[16];
    const float* b2     = (const float*)d_in[17];
    const float* w3     = (const float*)d_in[18];
    const float* b3     = (const float*)d_in[19];
    float* outp = (float*)d_out;

    float* part = (float*)d_ws;                               // [2][16][1024] f32
    float* PL   = (float*)((char*)d_ws + 131072);             // 1024*32 f32
    float* PR   = (float*)((char*)d_ws + 262144);             // 1024*32 f32
    float* Kp   = (float*)((char*)d_ws + 393216);             // 3*3*32 f32
    short* U16  = (short*)((char*)d_ws + 394368);             // 3*1024*32 f16
    short* V16  = (short*)((char*)d_ws + 590976);             // 3*1024*32 f16

    dim3 g1(8, 16, 2);
    gnn_kernel<<<g1, 512, 0, stream>>>(lig_nf, lig_ef, rec_nf, rec_ef,
                                       Wn, We, bn, be, part);
    dim3 g2(128, 2);
    proj_kernel<<<g2, 256, 0, stream>>>(lig_nf, rec_nf, W_hopi, PL, PR);
    cveck_kernel<<<1, 256, 0, stream>>>(W_hopi, b_hopi, w1, b1, part, Kp);
    dim3 g4(16, 3, 2);
    uv_kernel<<<g4, 256, 0, stream>>>(PL, PR, w1, U16, V16);
    dim3 g3(64, 64);
    conv_kernel<<<g3, 512, 0, stream>>>(U16, V16, Kp, w2, b2, w3, b3, outp);
}